// Round 8
// baseline (207.121 us; speedup 1.0000x reference)
//
#include <hip/hip_runtime.h>
#include <hip/hip_bf16.h>

// ---------------------------------------------------------------------------
// LogicLayer fused implementation (MI355X / gfx950)
// B=4, N=48, C=16, H=64; CIN={48,64,128,192}, COUT=16
// Round-8 == round-7 resubmit (GPU acquisition timed out; no data).
// y3's scattered x3 gathers (120MB @ 1.7TB/s, 71us) replaced by contiguous
// bf16 reads from three pre-permuted copies (perm3_kernel):
//   X0[b,m1,m2,m3] = bf16(x3)          (natural)
//   XA[b,m1,m3,m2] -> XA[b,i,j,k] = x3[b,i,k,j]
//   XB[b,m2,m3,m1] -> XB[b,i,j,k] = x3[b,k,i,j]
// Slice q0/q2 from X0, q1/q4 from XA, q3/q5 from XB -- all [48x16] bf16
// contiguous blocks.  Identical rounding (RNE moved to perm3).
// ---------------------------------------------------------------------------

typedef __bf16 bf16x8 __attribute__((ext_vector_type(8)));
typedef unsigned short us8 __attribute__((ext_vector_type(8)));
typedef float f32x4 __attribute__((ext_vector_type(4)));

#define NPAIR 589824    // 4*48*48*64
#define NRED3 294912    // 4*48*48*32 (shorts)
#define NX3   7077888   // 4*48*48*48*16 (shorts per x3 copy)

__device__ __forceinline__ unsigned short f2bf(float f) {
    __hip_bfloat16 h = __float2bfloat16(f);   // RNE
    return __builtin_bit_cast(unsigned short, h);
}
__device__ __forceinline__ unsigned int pk2(float a, float b) {
    return (unsigned int)f2bf(a) | ((unsigned int)f2bf(b) << 16);
}
__device__ __forceinline__ float bflo(unsigned int u) {
    return __builtin_bit_cast(float, u << 16);
}
__device__ __forceinline__ float bfhi(unsigned int u) {
    return __builtin_bit_cast(float, u & 0xffff0000u);
}
__device__ __forceinline__ float sigmoidf_(float z) {
    return 1.0f / (1.0f + __expf(-z));
}
__device__ __forceinline__ bf16x8 ld_bf8(const unsigned short* p) {
    return __builtin_bit_cast(bf16x8, *(const us8*)p);
}
__device__ __forceinline__ bf16x8 pack8(float4 a, float4 b) {
    us8 u;
    u[0] = f2bf(a.x); u[1] = f2bf(a.y); u[2] = f2bf(a.z); u[3] = f2bf(a.w);
    u[4] = f2bf(b.x); u[5] = f2bf(b.y); u[6] = f2bf(b.z); u[7] = f2bf(b.w);
    return __builtin_bit_cast(bf16x8, u);
}

// ---------------------------------------------------------------------------
// perm3: x3 (fp32, natural) -> three bf16 copies.  9216 blocks x 192 thr,
// one float4 read + three uint2 writes per thread.
// ---------------------------------------------------------------------------
__global__ __launch_bounds__(192) void perm3_kernel(
    const float* __restrict__ x3,
    unsigned short* __restrict__ X0, unsigned short* __restrict__ XA,
    unsigned short* __restrict__ XB)
{
    const int g = blockIdx.x;                 // (b*48+m1)*48+m2
    const int m2 = g % 48, t1 = g / 48, m1 = t1 % 48, b = t1 / 48;
    const int t = threadIdx.x;
    const int m3 = t >> 2, cq = (t & 3) * 4;
    const float4 v = *(const float4*)(x3 + (size_t)g * 768 + m3 * 16 + cq);
    const uint2 u = make_uint2(pk2(v.x, v.y), pk2(v.z, v.w));
    *(uint2*)(X0 + (size_t)g * 768 + m3 * 16 + cq) = u;
    *(uint2*)(XA + (((size_t)(b * 48 + m1) * 48 + m3) * 48 + m2) * 16 + cq) = u;
    *(uint2*)(XB + (((size_t)(b * 48 + m2) * 48 + m3) * 48 + m1) * 16 + cq) = u;
}

// ---------------------------------------------------------------------------
// Phase A: pair tensors for y3 (verified round 4/5/6).
// ---------------------------------------------------------------------------
__global__ __launch_bounds__(256) void phaseA_kernel(
    const float* __restrict__ x2, const float* __restrict__ W1,
    const float* __restrict__ b1,
    float* __restrict__ wsA, unsigned short* __restrict__ wsB,
    unsigned short* __restrict__ wsC)
{
    __shared__ float xr[4][32];
    const int t = threadIdx.x;
    if (t < 128) {
        const int pr2 = t >> 5, c = t & 31;
        const int gg = blockIdx.x * 4 + pr2;
        const int bb = gg / 2304, pp2 = gg % 2304, P = pp2 / 48, Q = pp2 % 48;
        const float* base = x2 + (size_t)bb * 36864;
        xr[pr2][c] = (c < 16) ? base[(P * 48 + Q) * 16 + c]
                              : base[(Q * 48 + P) * 16 + (c - 16)];
    }
    __syncthreads();
    const int pr = t >> 6, h = t & 63;
    const int g = blockIdx.x * 4 + pr;
    float a = b1[h], bacc = 0.f, cacc = 0.f;
#pragma unroll
    for (int c = 0; c < 16; ++c) {
        const float xpq = xr[pr][c], xqp = xr[pr][16 + c];
        a    += xpq * W1[(  0 + c) * 64 + h] + xqp * W1[( 64 + c) * 64 + h];
        bacc += xpq * W1[( 32 + c) * 64 + h] + xqp * W1[( 96 + c) * 64 + h];
        cacc += xpq * W1[(128 + c) * 64 + h] + xqp * W1[(160 + c) * 64 + h];
    }
    const size_t o = (size_t)g * 64 + h;
    wsA[o] = a;
    wsB[o] = f2bf(bacc);
    wsC[o] = f2bf(cacc);
}

// ---------------------------------------------------------------------------
// y3: 2304 blocks x 192 thr, 4 tiles each, barrier-free main loop.
// x-frags are contiguous 16B bf16 loads from X0/XA/XB:
//   p0: lo X0(i,j)  hi XA(i,j)   (q0 x3[b,i,j,k] / q1 x3[b,i,k,j])
//   p1: lo X0(j,i)  hi XB(i,j)   (q2 x3[b,j,i,k] / q3 x3[b,k,i,j])
//   p2: lo XA(j,i)  hi XB(j,i)   (q4 x3[b,j,k,i] / q5 x3[b,k,j,i])
// ---------------------------------------------------------------------------
__global__ __launch_bounds__(192, 3) void y3_kernel(
    const unsigned short* __restrict__ X0,
    const unsigned short* __restrict__ XA,
    const unsigned short* __restrict__ XB,
    const float* __restrict__ W1, const float* __restrict__ W2,
    const float* __restrict__ b2,
    const float* __restrict__ wsA,
    const unsigned short* __restrict__ wsB,
    const unsigned short* __restrict__ wsC,
    float* __restrict__ out)
{
    __shared__ __align__(16) unsigned short w1t[64 * 104];   // [h][kk], one-time
    const int t = threadIdx.x;
    const int w = t >> 6, lane = t & 63, lr = lane & 15, lg = lane >> 4;

#pragma unroll
    for (int p = 0; p < 16; ++p) {
        const int e = p * 192 + t;
        const int h = e & 63, kk = (e >> 6) * 2;
        const int r0 = 16 + ((kk >> 4) << 5) + (kk & 15);
        *(unsigned int*)(w1t + h * 104 + kk) =
            pk2(W1[r0 * 64 + h], W1[(r0 + 1) * 64 + h]);
    }
    __syncthreads();   // only barrier in the kernel

    bf16x8 w1f[4][3];
#pragma unroll
    for (int n = 0; n < 4; ++n)
#pragma unroll
        for (int ks = 0; ks < 3; ++ks)
            w1f[n][ks] = ld_bf8(w1t + (16 * n + lr) * 104 + 32 * ks + 8 * lg);

    bf16x8 w2f[2];
#pragma unroll
    for (int m = 0; m < 2; ++m) {
        us8 u;
#pragma unroll
        for (int e = 0; e < 8; ++e) {
            const int ch = 16 * (e >> 1) + 4 * lg + 2 * (e & 1) + m;
            u[e] = f2bf(W2[ch * 16 + lr]);
        }
        w2f[m] = __builtin_bit_cast(bf16x8, u);
    }
    const float4 b2v = *(const float4*)(b2 + 4 * lg);
    const int row = 16 * w + lr;
    const int roff = row * 16 + 8 * (lg & 1);
    const bool hi = (lg >> 1) != 0;

    for (int it = 0; it < 4; ++it) {
        const int g = blockIdx.x * 4 + it;
        const int b = g / 2304, pp = g % 2304, i = pp / 48, j = pp % 48;
        const size_t blkIJ = ((size_t)(b * 48 + i) * 48 + j) * 768;
        const size_t blkJI = ((size_t)(b * 48 + j) * 48 + i) * 768;
        const unsigned short* p0 = (hi ? XA + blkIJ : X0 + blkIJ) + roff;
        const unsigned short* p1 = (hi ? XB + blkIJ : X0 + blkJI) + roff;
        const unsigned short* p2 = (hi ? XB + blkJI : XA + blkJI) + roff;
        const bf16x8 xf0 = ld_bf8(p0);
        const bf16x8 xf1 = ld_bf8(p1);
        const bf16x8 xf2 = ld_bf8(p2);

        f32x4 acc[4];
#pragma unroll
        for (int n = 0; n < 4; ++n) {
            acc[n] = f32x4{0.f, 0.f, 0.f, 0.f};
            acc[n] = __builtin_amdgcn_mfma_f32_16x16x32_bf16(w1f[n][0], xf0, acc[n], 0, 0, 0);
            acc[n] = __builtin_amdgcn_mfma_f32_16x16x32_bf16(w1f[n][1], xf1, acc[n], 0, 0, 0);
            acc[n] = __builtin_amdgcn_mfma_f32_16x16x32_bf16(w1f[n][2], xf2, acc[n], 0, 0, 0);
        }
        const size_t baseB = ((size_t)((b * 48 + i) * 48 + row)) * 64 + 4 * lg;
        const size_t baseC = ((size_t)((b * 48 + j) * 48 + row)) * 64 + 4 * lg;
        const size_t baseA = ((size_t)((b * 48 + i) * 48 + j)) * 64 + 4 * lg;
#pragma unroll
        for (int n = 0; n < 4; ++n) {
            const uint2 Bu = *(const uint2*)(wsB + baseB + 16 * n);
            const uint2 Cu = *(const uint2*)(wsC + baseC + 16 * n);
            const float4 Au = *(const float4*)(wsA + baseA + 16 * n);
            acc[n][0] = fmaxf(acc[n][0] + Au.x + bflo(Bu.x) + bflo(Cu.x), 0.f);
            acc[n][1] = fmaxf(acc[n][1] + Au.y + bfhi(Bu.x) + bfhi(Cu.x), 0.f);
            acc[n][2] = fmaxf(acc[n][2] + Au.z + bflo(Bu.y) + bflo(Cu.y), 0.f);
            acc[n][3] = fmaxf(acc[n][3] + Au.w + bfhi(Bu.y) + bfhi(Cu.y), 0.f);
        }
        bf16x8 hf[2];
#pragma unroll
        for (int m = 0; m < 2; ++m) {
            us8 u;
#pragma unroll
            for (int e = 0; e < 8; ++e)
                u[e] = f2bf(acc[e >> 1][2 * (e & 1) + m]);
            hf[m] = __builtin_bit_cast(bf16x8, u);
        }
        f32x4 o2 = {0.f, 0.f, 0.f, 0.f};
        o2 = __builtin_amdgcn_mfma_f32_16x16x32_bf16(w2f[0], hf[0], o2, 0, 0, 0);
        o2 = __builtin_amdgcn_mfma_f32_16x16x32_bf16(w2f[1], hf[1], o2, 0, 0, 0);
        float4 ov;
        ov.x = sigmoidf_(o2[0] + b2v.x);
        ov.y = sigmoidf_(o2[1] + b2v.y);
        ov.z = sigmoidf_(o2[2] + b2v.z);
        ov.w = sigmoidf_(o2[3] + b2v.w);
        *(float4*)(out + (size_t)g * 768 + row * 16 + 4 * lg) = ov;
    }
}

// ---------------------------------------------------------------------------
// y3 gather version (round-6 verified) — middle-tier fallback.
// ---------------------------------------------------------------------------
__global__ __launch_bounds__(192, 3) void y3_gather_kernel(
    const float* __restrict__ x3,
    const float* __restrict__ W1, const float* __restrict__ W2,
    const float* __restrict__ b2,
    const float* __restrict__ wsA,
    const unsigned short* __restrict__ wsB,
    const unsigned short* __restrict__ wsC,
    float* __restrict__ out)
{
    __shared__ __align__(16) unsigned short w1t[64 * 104];
    const int t = threadIdx.x;
    const int w = t >> 6, lane = t & 63, lr = lane & 15, lg = lane >> 4;
#pragma unroll
    for (int p = 0; p < 16; ++p) {
        const int e = p * 192 + t;
        const int h = e & 63, kk = (e >> 6) * 2;
        const int r0 = 16 + ((kk >> 4) << 5) + (kk & 15);
        *(unsigned int*)(w1t + h * 104 + kk) =
            pk2(W1[r0 * 64 + h], W1[(r0 + 1) * 64 + h]);
    }
    __syncthreads();
    bf16x8 w1f[4][3];
#pragma unroll
    for (int n = 0; n < 4; ++n)
#pragma unroll
        for (int ks = 0; ks < 3; ++ks)
            w1f[n][ks] = ld_bf8(w1t + (16 * n + lr) * 104 + 32 * ks + 8 * lg);
    bf16x8 w2f[2];
#pragma unroll
    for (int m = 0; m < 2; ++m) {
        us8 u;
#pragma unroll
        for (int e = 0; e < 8; ++e) {
            const int ch = 16 * (e >> 1) + 4 * lg + 2 * (e & 1) + m;
            u[e] = f2bf(W2[ch * 16 + lr]);
        }
        w2f[m] = __builtin_bit_cast(bf16x8, u);
    }
    const float4 b2v = *(const float4*)(b2 + 4 * lg);
    const int row = 16 * w + lr;
    const int c0 = 8 * (lg & 1);
    const bool hi = (lg >> 1) != 0;
    for (int it = 0; it < 4; ++it) {
        const int g = blockIdx.x * 4 + it;
        const int b = g / 2304, pp = g % 2304, i = pp / 48, j = pp % 48;
        const float* xb3 = x3 + (size_t)b * 1769472;
        const int sb0 = i * 36864 + j * 768 + row * 16;
        const int sb1 = i * 36864 + row * 768 + j * 16;
        const int sb2 = j * 36864 + i * 768 + row * 16;
        const int sb3 = row * 36864 + i * 768 + j * 16;
        const int sb4 = j * 36864 + row * 768 + i * 16;
        const int sb5 = row * 36864 + j * 768 + i * 16;
        const float* p0 = xb3 + (hi ? sb1 : sb0) + c0;
        const float* p1 = xb3 + (hi ? sb3 : sb2) + c0;
        const float* p2 = xb3 + (hi ? sb5 : sb4) + c0;
        const bf16x8 xf0 = pack8(*(const float4*)p0, *(const float4*)(p0 + 4));
        const bf16x8 xf1 = pack8(*(const float4*)p1, *(const float4*)(p1 + 4));
        const bf16x8 xf2 = pack8(*(const float4*)p2, *(const float4*)(p2 + 4));
        f32x4 acc[4];
#pragma unroll
        for (int n = 0; n < 4; ++n) {
            acc[n] = f32x4{0.f, 0.f, 0.f, 0.f};
            acc[n] = __builtin_amdgcn_mfma_f32_16x16x32_bf16(w1f[n][0], xf0, acc[n], 0, 0, 0);
            acc[n] = __builtin_amdgcn_mfma_f32_16x16x32_bf16(w1f[n][1], xf1, acc[n], 0, 0, 0);
            acc[n] = __builtin_amdgcn_mfma_f32_16x16x32_bf16(w1f[n][2], xf2, acc[n], 0, 0, 0);
        }
        const size_t baseB = ((size_t)((b * 48 + i) * 48 + row)) * 64 + 4 * lg;
        const size_t baseC = ((size_t)((b * 48 + j) * 48 + row)) * 64 + 4 * lg;
        const size_t baseA = ((size_t)((b * 48 + i) * 48 + j)) * 64 + 4 * lg;
#pragma unroll
        for (int n = 0; n < 4; ++n) {
            const uint2 Bu = *(const uint2*)(wsB + baseB + 16 * n);
            const uint2 Cu = *(const uint2*)(wsC + baseC + 16 * n);
            const float4 Au = *(const float4*)(wsA + baseA + 16 * n);
            acc[n][0] = fmaxf(acc[n][0] + Au.x + bflo(Bu.x) + bflo(Cu.x), 0.f);
            acc[n][1] = fmaxf(acc[n][1] + Au.y + bfhi(Bu.x) + bfhi(Cu.x), 0.f);
            acc[n][2] = fmaxf(acc[n][2] + Au.z + bflo(Bu.y) + bflo(Cu.y), 0.f);
            acc[n][3] = fmaxf(acc[n][3] + Au.w + bfhi(Bu.y) + bfhi(Cu.y), 0.f);
        }
        bf16x8 hf[2];
#pragma unroll
        for (int m = 0; m < 2; ++m) {
            us8 u;
#pragma unroll
            for (int e = 0; e < 8; ++e)
                u[e] = f2bf(acc[e >> 1][2 * (e & 1) + m]);
            hf[m] = __builtin_bit_cast(bf16x8, u);
        }
        f32x4 o2 = {0.f, 0.f, 0.f, 0.f};
        o2 = __builtin_amdgcn_mfma_f32_16x16x32_bf16(w2f[0], hf[0], o2, 0, 0, 0);
        o2 = __builtin_amdgcn_mfma_f32_16x16x32_bf16(w2f[1], hf[1], o2, 0, 0, 0);
        float4 ov;
        ov.x = sigmoidf_(o2[0] + b2v.x);
        ov.y = sigmoidf_(o2[1] + b2v.y);
        ov.z = sigmoidf_(o2[2] + b2v.z);
        ov.w = sigmoidf_(o2[3] + b2v.w);
        *(float4*)(out + (size_t)g * 768 + row * 16 + 4 * lg) = ov;
    }
}

// ---------------------------------------------------------------------------
// red3 (verified round 6)
// ---------------------------------------------------------------------------
__global__ __launch_bounds__(256) void red3_kernel(
    const float* __restrict__ x3, unsigned short* __restrict__ red3)
{
    const int slot = blockIdx.x * 256 + threadIdx.x;
    const int c = slot & 15;
    const int q = slot >> 4;          // pi*48 + j, pi = b*48+i
    const int j = q % 48, pi = q / 48, i = pi % 48;
    const float* p = x3 + (size_t)q * 768 + c;
    float ex = -__builtin_inff(), fa = __builtin_inff();
    const bool mij = (i != j);
#pragma unroll 8
    for (int k = 0; k < 48; ++k) {
        const bool m = mij & (k != i) & (k != j);
        const float v = p[k * 16];
        ex = fmaxf(ex, m ? v : 0.f);
        fa = fminf(fa, m ? v : 1.f);
    }
    *(unsigned int*)(red3 + (size_t)q * 32 + 2 * c) = pk2(ex, fa);
}

// ---------------------------------------------------------------------------
// y2 MLP (verified round 5/6)
// ---------------------------------------------------------------------------
__global__ __launch_bounds__(192, 3) void y2_mlp_kernel(
    const float* __restrict__ x1, const float* __restrict__ x2,
    const float* __restrict__ W1, const float* __restrict__ b1,
    const float* __restrict__ W2, const float* __restrict__ b2,
    const unsigned short* __restrict__ red3, float* __restrict__ out)
{
    __shared__ __align__(16) unsigned short w1t[64 * 136];
    const int t = threadIdx.x;
    const int w = t >> 6, lane = t & 63, lr = lane & 15, lg = lane >> 4;

#pragma unroll
    for (int p = 0; p < 22; ++p) {
        const int e = p * 192 + t;
        if (e < 4096) {
            const int h = e & 63, k2 = e >> 6;
            *(unsigned int*)(w1t + h * 136 + 2 * k2) =
                pk2(W1[(2 * k2) * 64 + h], W1[(2 * k2 + 1) * 64 + h]);
        }
    }
    __syncthreads();

    bf16x8 w1f[4][4];
#pragma unroll
    for (int n = 0; n < 4; ++n)
#pragma unroll
        for (int ks = 0; ks < 4; ++ks)
            w1f[n][ks] = ld_bf8(w1t + (16 * n + lr) * 136 + 32 * ks + 8 * lg);

    bf16x8 w2f[2];
#pragma unroll
    for (int m = 0; m < 2; ++m) {
        us8 u;
#pragma unroll
        for (int e = 0; e < 8; ++e) {
            const int ch = 16 * (e >> 1) + 4 * lg + 2 * (e & 1) + m;
            u[e] = f2bf(W2[ch * 16 + lr]);
        }
        w2f[m] = __builtin_bit_cast(bf16x8, u);
    }
    float4 b1v[4];
#pragma unroll
    for (int n = 0; n < 4; ++n) b1v[n] = *(const float4*)(b1 + 16 * n + 4 * lg);
    const float4 b2v = *(const float4*)(b2 + 4 * lg);

    const int bq = blockIdx.x;                 // b*48 + i
    const int b = bq / 48, i = bq % 48;
    const float* x2b = x2 + (size_t)b * 36864;
    const int row = 16 * w + lr;               // = j
    const int j = row;
    const int c0 = 8 * (lg & 1);
    const bool hi = (lg >> 1) != 0;

    const float* a0 = hi ? (x2b + (i * 48 + j) * 16 + c0) : (x1 + (b * 48 + i) * 16 + c0);
    const float* a2 = hi ? (x2b + (j * 48 + i) * 16 + c0) : (x1 + (b * 48 + j) * 16 + c0);
    const unsigned short* r1 = red3 + ((size_t)(b * 48 + i) * 48 + j) * 32 + (hi ? 16 : 0) + c0;
    const unsigned short* r3 = red3 + ((size_t)(b * 48 + j) * 48 + i) * 32 + (hi ? 16 : 0) + c0;

    const bf16x8 xf0 = pack8(*(const float4*)a0, *(const float4*)(a0 + 4));
    const bf16x8 xf1 = ld_bf8(r1);
    const bf16x8 xf2 = pack8(*(const float4*)a2, *(const float4*)(a2 + 4));
    const bf16x8 xf3 = ld_bf8(r3);

    f32x4 acc[4];
#pragma unroll
    for (int n = 0; n < 4; ++n) {
        acc[n] = f32x4{0.f, 0.f, 0.f, 0.f};
        acc[n] = __builtin_amdgcn_mfma_f32_16x16x32_bf16(w1f[n][0], xf0, acc[n], 0, 0, 0);
        acc[n] = __builtin_amdgcn_mfma_f32_16x16x32_bf16(w1f[n][1], xf1, acc[n], 0, 0, 0);
        acc[n] = __builtin_amdgcn_mfma_f32_16x16x32_bf16(w1f[n][2], xf2, acc[n], 0, 0, 0);
        acc[n] = __builtin_amdgcn_mfma_f32_16x16x32_bf16(w1f[n][3], xf3, acc[n], 0, 0, 0);
    }
#pragma unroll
    for (int n = 0; n < 4; ++n) {
        acc[n][0] = fmaxf(acc[n][0] + b1v[n].x, 0.f);
        acc[n][1] = fmaxf(acc[n][1] + b1v[n].y, 0.f);
        acc[n][2] = fmaxf(acc[n][2] + b1v[n].z, 0.f);
        acc[n][3] = fmaxf(acc[n][3] + b1v[n].w, 0.f);
    }
    bf16x8 hf[2];
#pragma unroll
    for (int m = 0; m < 2; ++m) {
        us8 u;
#pragma unroll
        for (int e = 0; e < 8; ++e)
            u[e] = f2bf(acc[e >> 1][2 * (e & 1) + m]);
        hf[m] = __builtin_bit_cast(bf16x8, u);
    }
    f32x4 o2 = {0.f, 0.f, 0.f, 0.f};
    o2 = __builtin_amdgcn_mfma_f32_16x16x32_bf16(w2f[0], hf[0], o2, 0, 0, 0);
    o2 = __builtin_amdgcn_mfma_f32_16x16x32_bf16(w2f[1], hf[1], o2, 0, 0, 0);
    float4 ov;
    ov.x = sigmoidf_(o2[0] + b2v.x);
    ov.y = sigmoidf_(o2[1] + b2v.y);
    ov.z = sigmoidf_(o2[2] + b2v.z);
    ov.w = sigmoidf_(o2[3] + b2v.w);
    *(float4*)(out + ((size_t)bq * 48 + row) * 16 + 4 * lg) = ov;
}

// ---------------------------------------------------------------------------
// y0 + y1 (verified round 6)
// ---------------------------------------------------------------------------
__global__ __launch_bounds__(192, 1) void y01_kernel(
    const float* __restrict__ x0, const float* __restrict__ x1,
    const float* __restrict__ x2,
    const float* __restrict__ W1_0, const float* __restrict__ b1_0,
    const float* __restrict__ W2_0, const float* __restrict__ b2_0,
    const float* __restrict__ W1_1, const float* __restrict__ b1_1,
    const float* __restrict__ W2_1, const float* __restrict__ b2_1,
    float* __restrict__ out)
{
    const int t = threadIdx.x;
    if (blockIdx.x < 4) {
        __shared__ __align__(16) unsigned short w1t[64 * 72];
        __shared__ __align__(16) unsigned short red2l[48 * 32];
        const int b = blockIdx.x;
#pragma unroll
        for (int p = 0; p < 11; ++p) {
            const int e = p * 192 + t;
            if (e < 2048) {
                const int h = e & 63, k2 = e >> 6;
                *(unsigned int*)(w1t + h * 72 + 2 * k2) =
                    pk2(W1_1[(2 * k2) * 64 + h], W1_1[(2 * k2 + 1) * 64 + h]);
            }
        }
        const float* x2b = x2 + (size_t)b * 36864;
#pragma unroll
        for (int s4 = 0; s4 < 4; ++s4) {
            const int s = t + 192 * s4;            // 0..767
            const int i = s >> 4, c = s & 15;
            const float* p = x2b + i * 768 + c;
            float ex = -__builtin_inff(), fa = __builtin_inff();
#pragma unroll 8
            for (int jj = 0; jj < 48; ++jj) {
                const bool m = (jj != i);
                const float v = p[jj * 16];
                ex = fmaxf(ex, m ? v : 0.f);
                fa = fminf(fa, m ? v : 1.f);
            }
            *(unsigned int*)(red2l + i * 32 + 2 * c) = pk2(ex, fa);
        }
        __syncthreads();

        const int w = t >> 6, lane = t & 63, lr = lane & 15, lg = lane >> 4;
        const int i = 16 * w + lr;
        const int rho = b * 48 + i;
        bf16x8 w1f[4][2];
#pragma unroll
        for (int n = 0; n < 4; ++n)
#pragma unroll
            for (int ks = 0; ks < 2; ++ks)
                w1f[n][ks] = ld_bf8(w1t + (16 * n + lr) * 72 + 32 * ks + 8 * lg);
        bf16x8 w2f[2];
#pragma unroll
        for (int m = 0; m < 2; ++m) {
            us8 u;
#pragma unroll
            for (int e = 0; e < 8; ++e) {
                const int ch = 16 * (e >> 1) + 4 * lg + 2 * (e & 1) + m;
                u[e] = f2bf(W2_1[ch * 16 + lr]);
            }
            w2f[m] = __builtin_bit_cast(bf16x8, u);
        }
        float4 b1v[4];
#pragma unroll
        for (int n = 0; n < 4; ++n) b1v[n] = *(const float4*)(b1_1 + 16 * n + 4 * lg);
        const float4 b2v = *(const float4*)(b2_1 + 4 * lg);

        const int c0 = 8 * (lg & 1);
        const float* a0 = (lg < 2) ? (x0 + b * 16 + c0) : (x1 + rho * 16 + c0);
        const bf16x8 xf0 = pack8(*(const float4*)a0, *(const float4*)(a0 + 4));
        const bf16x8 xf1 = ld_bf8(red2l + i * 32 + 8 * lg);

        f32x4 acc[4];
#pragma unroll
        for (int n = 0; n < 4; ++n) {
            acc[n] = f32x4{0.f, 0.f, 0.f, 0.f};
            acc[n] = __builtin_amdgcn_mfma_f32_16x16x32_bf16(w1f[n][0], xf0, acc[n], 0, 0, 0);
            acc[n] = __builtin_amdgcn_mfma_f32_16x16x32_bf16(w1f[n][1], xf1, acc[n], 0, 0, 0);
        }
#pragma unroll
        for (int n = 0; n < 4; ++n) {
            acc[n][0] = fmaxf(acc[n][0] + b1v[n].x, 0.f);
            acc[n][1] = fmaxf(acc[n][1] + b1v[n].y, 0.f);
            acc[n][2] = fmaxf(acc[n][2] + b1v[n].z, 0.f);
            acc[n][3] = fmaxf(acc[n][3] + b1v[n].w, 0.f);
        }
        bf16x8 hf[2];
#pragma unroll
        for (int m = 0; m < 2; ++m) {
            us8 u;
#pragma unroll
            for (int e = 0; e < 8; ++e)
                u[e] = f2bf(acc[e >> 1][2 * (e & 1) + m]);
            hf[m] = __builtin_bit_cast(bf16x8, u);
        }
        f32x4 o2 = {0.f, 0.f, 0.f, 0.f};
        o2 = __builtin_amdgcn_mfma_f32_16x16x32_bf16(w2f[0], hf[0], o2, 0, 0, 0);
        o2 = __builtin_amdgcn_mfma_f32_16x16x32_bf16(w2f[1], hf[1], o2, 0, 0, 0);
        float4 ov;
        ov.x = sigmoidf_(o2[0] + b2v.x);
        ov.y = sigmoidf_(o2[1] + b2v.y);
        ov.z = sigmoidf_(o2[2] + b2v.z);
        ov.w = sigmoidf_(o2[3] + b2v.w);
        *(float4*)(out + 64 + (size_t)rho * 16 + 4 * lg) = ov;
    } else {
        __shared__ float t0l[4][56];
        __shared__ float hl[4][72];
        if (t < 64) {
            const int b = t >> 4, c = t & 15;
            const float* p = x1 + b * 768 + c;
            float ex = -__builtin_inff(), fa = __builtin_inff();
#pragma unroll 8
            for (int n = 0; n < 48; ++n) {
                const float v = p[n * 16];
                ex = fmaxf(ex, v);
                fa = fminf(fa, v);
            }
            t0l[b][c] = x0[b * 16 + c];
            t0l[b][16 + 2 * c] = ex;
            t0l[b][17 + 2 * c] = fa;
        }
        __syncthreads();
        if (t < 64) {
            const int h = t;
            float ac0 = b1_0[h], ac1 = ac0, ac2 = ac0, ac3 = ac0;
#pragma unroll
            for (int c = 0; c < 48; ++c) {
                const float wv = W1_0[c * 64 + h];
                ac0 = fmaf(t0l[0][c], wv, ac0);
                ac1 = fmaf(t0l[1][c], wv, ac1);
                ac2 = fmaf(t0l[2][c], wv, ac2);
                ac3 = fmaf(t0l[3][c], wv, ac3);
            }
            hl[0][h] = fmaxf(ac0, 0.f);
            hl[1][h] = fmaxf(ac1, 0.f);
            hl[2][h] = fmaxf(ac2, 0.f);
            hl[3][h] = fmaxf(ac3, 0.f);
        }
        __syncthreads();
        if (t < 64) {
            const int b = t >> 4, o = t & 15;
            float a = b2_0[o];
#pragma unroll
            for (int h = 0; h < 64; ++h)
                a = fmaf(hl[b][h], W2_0[h * 16 + o], a);
            out[b * 16 + o] = sigmoidf_(a);
        }
    }
}

// ---------------------------------------------------------------------------
// Lowest-tier fallbacks (verified round 1/4), used only if ws too small.
// ---------------------------------------------------------------------------
template <int NK>
__device__ __forceinline__ void mlp_head(
    const unsigned short* lds_in, const unsigned short* lds_w1t,
    const unsigned short* lds_w2t, const float* lds_b1, const float* lds_b2,
    unsigned short* lds_h, float* outp)
{
    constexpr int S = NK * 32 + 8;
    const int t = threadIdx.x;
    const int w = t >> 6, lr = t & 15, lg = (t >> 4) & 3;
    f32x4 acc0 = {0.f, 0.f, 0.f, 0.f};
    f32x4 acc1 = acc0, acc2 = acc0, acc3 = acc0;
    const unsigned short* pa = lds_in + (16 * w + lr) * S + lg * 8;
    const unsigned short* pb = lds_w1t + lr * S + lg * 8;
#pragma unroll
    for (int ks = 0; ks < NK; ++ks) {
        bf16x8 a = ld_bf8(pa + ks * 32);
        acc0 = __builtin_amdgcn_mfma_f32_16x16x32_bf16(a, ld_bf8(pb + 0 * 16 * S + ks * 32), acc0, 0, 0, 0);
        acc1 = __builtin_amdgcn_mfma_f32_16x16x32_bf16(a, ld_bf8(pb + 1 * 16 * S + ks * 32), acc1, 0, 0, 0);
        acc2 = __builtin_amdgcn_mfma_f32_16x16x32_bf16(a, ld_bf8(pb + 2 * 16 * S + ks * 32), acc2, 0, 0, 0);
        acc3 = __builtin_amdgcn_mfma_f32_16x16x32_bf16(a, ld_bf8(pb + 3 * 16 * S + ks * 32), acc3, 0, 0, 0);
    }
    const int hrow = 16 * w + lg * 4;
#pragma unroll
    for (int r = 0; r < 4; ++r) {
        lds_h[(hrow + r) * 72 +  0 + lr] = f2bf(fmaxf(acc0[r] + lds_b1[ 0 + lr], 0.f));
        lds_h[(hrow + r) * 72 + 16 + lr] = f2bf(fmaxf(acc1[r] + lds_b1[16 + lr], 0.f));
        lds_h[(hrow + r) * 72 + 32 + lr] = f2bf(fmaxf(acc2[r] + lds_b1[32 + lr], 0.f));
        lds_h[(hrow + r) * 72 + 48 + lr] = f2bf(fmaxf(acc3[r] + lds_b1[48 + lr], 0.f));
    }
    __syncthreads();
    f32x4 o = {0.f, 0.f, 0.f, 0.f};
#pragma unroll
    for (int ks = 0; ks < 2; ++ks) {
        bf16x8 a = ld_bf8(lds_h + (16 * w + lr) * 72 + ks * 32 + lg * 8);
        bf16x8 b = ld_bf8(lds_w2t + lr * 72 + ks * 32 + lg * 8);
        o = __builtin_amdgcn_mfma_f32_16x16x32_bf16(a, b, o, 0, 0, 0);
    }
    const float b2v = lds_b2[lr];
#pragma unroll
    for (int r = 0; r < 4; ++r)
        outp[(hrow + r) * 16 + lr] = sigmoidf_(o[r] + b2v);
}

__global__ __launch_bounds__(192) void y3_fallback_kernel(
    const float* __restrict__ x2, const float* __restrict__ x3,
    const float* __restrict__ W1, const float* __restrict__ b1,
    const float* __restrict__ W2, const float* __restrict__ b2,
    float* __restrict__ out)
{
    __shared__ __align__(16) unsigned short lds_in[48 * 200];
    __shared__ __align__(16) unsigned short lds_w1t[64 * 200];
    __shared__ __align__(16) unsigned short lds_w2t[16 * 72];
    __shared__ __align__(16) unsigned short lds_h[48 * 72];
    __shared__ float lds_b1[64];
    __shared__ float lds_b2[16];
    const int t = threadIdx.x;
#pragma unroll 4
    for (int p = 0; p < 32; ++p) {
        int e = p * 192 + t;
        int h = e & 63, c2 = e >> 6;
        *(unsigned int*)(lds_w1t + h * 200 + 2 * c2) =
            pk2(W1[(2 * c2) * 64 + h], W1[(2 * c2 + 1) * 64 + h]);
    }
    for (int p = 0; p < 3; ++p) {
        int e = p * 192 + t;
        if (e < 512) {
            int n = e & 15, k2 = e >> 4;
            *(unsigned int*)(lds_w2t + n * 72 + 2 * k2) =
                pk2(W2[(2 * k2) * 16 + n], W2[(2 * k2 + 1) * 16 + n]);
        }
    }
    if (t < 64) lds_b1[t] = b1[t];
    if (t < 16) lds_b2[t] = b2[t];
    const int k = t >> 2, c4 = (t & 3) * 4;
#define STAGE3(PTR, BASE, KSTR, CH) do {                                       \
        const float4 v = *(const float4*)((PTR) + (BASE) + k * (KSTR) + c4);   \
        *(uint2*)(lds_in + k * 200 + (CH) + c4) =                              \
            make_uint2(pk2(v.x, v.y), pk2(v.z, v.w));                          \
    } while (0)
    for (int it = 0; it < 9; ++it) {
        const int g = blockIdx.x * 9 + it;
        const int b = g / 2304, rg = g % 2304, i = rg / 48, j = rg % 48;
        const float* xb2 = x2 + b * 36864;
        const float* xb3 = x3 + b * 1769472;
        __syncthreads();
        STAGE3(xb2, i * 768 + j * 16, 0,       0);
        STAGE3(xb3, i * 36864 + j * 768, 16,   16);
        STAGE3(xb2, i * 768, 16,               32);
        STAGE3(xb3, i * 36864 + j * 16, 768,   48);
        STAGE3(xb2, j * 768 + i * 16, 0,       64);
        STAGE3(xb3, j * 36864 + i * 768, 16,   80);
        STAGE3(xb2, i * 16, 768,               96);
        STAGE3(xb3, i * 768 + j * 16, 36864,   112);
        STAGE3(xb2, j * 768, 16,               128);
        STAGE3(xb3, j * 36864 + i * 16, 768,   144);
        STAGE3(xb2, j * 16, 768,               160);
        STAGE3(xb3, j * 768 + i * 16, 36864,   176);
        __syncthreads();
        mlp_head<6>(lds_in, lds_w1t, lds_w2t, lds_b1, lds_b2, lds_h,
                    out + (size_t)g * 768);
    }
#undef STAGE3
}

__global__ __launch_bounds__(192) void y2_kernel(
    const float* __restrict__ x1, const float* __restrict__ x2,
    const float* __restrict__ x3,
    const float* __restrict__ W1, const float* __restrict__ b1,
    const float* __restrict__ W2, const float* __restrict__ b2,
    float* __restrict__ out)
{
    __shared__ __align__(16) unsigned short lds_in[48 * 136];
    __shared__ __align__(16) unsigned short lds_w1t[64 * 136];
    __shared__ __align__(16) unsigned short lds_w2t[16 * 72];
    __shared__ __align__(16) unsigned short lds_h[48 * 72];
    __shared__ float lds_b1[64];
    __shared__ float lds_b2[16];
    const int t = threadIdx.x;
    const int b = blockIdx.x / 48, i = blockIdx.x % 48;
#pragma unroll 2
    for (int p = 0; p < 22; ++p) {
        int e = p * 192 + t;
        if (e < 4096) {
            int h = e & 63, c2 = e >> 6;
            *(unsigned int*)(lds_w1t + h * 136 + 2 * c2) =
                pk2(W1[(2 * c2) * 64 + h], W1[(2 * c2 + 1) * 64 + h]);
        }
    }
    for (int p = 0; p < 3; ++p) {
        int e = p * 192 + t;
        if (e < 512) {
            int n = e & 15, k2 = e >> 4;
            *(unsigned int*)(lds_w2t + n * 72 + 2 * k2) =
                pk2(W2[(2 * k2) * 16 + n], W2[(2 * k2 + 1) * 16 + n]);
        }
    }
    if (t < 64) lds_b1[t] = b1[t];
    if (t < 16) lds_b2[t] = b2[t];
    const int j = t >> 2, c4 = (t & 3) * 4;
    const float* xb2 = x2 + b * 36864;
#define STAGE2(PTR, BASE, JSTR, CH) do {                                       \
        const float4 v = *(const float4*)((PTR) + (BASE) + j * (JSTR) + c4);   \
        *(uint2*)(lds_in + j * 136 + (CH) + c4) =                              \
            make_uint2(pk2(v.x, v.y), pk2(v.z, v.w));                          \
    } while (0)
    STAGE2(x1, b * 768 + i * 16, 0,  0);
    STAGE2(xb2, i * 768, 16,         16);
    STAGE2(x1, b * 768, 16,          64);
    STAGE2(xb2, i * 16, 768,         80);
#undef STAGE2
    {
        const float* pa = x3 + b * 1769472 + (i * 48 + j) * 768 + c4;
        const float* pb = x3 + b * 1769472 + (j * 48 + i) * 768 + c4;
        float exa[4], faa[4], exb[4], fab[4];
#pragma unroll
        for (int u = 0; u < 4; ++u) {
            exa[u] = -__builtin_inff(); faa[u] = __builtin_inff();
            exb[u] = -__builtin_inff(); fab[u] = __builtin_inff();
        }
        for (int kk = 0; kk < 48; ++kk) {
            const bool m = (i != j) & (i != kk) & (j != kk);
            const float4 va = *(const float4*)(pa + kk * 16);
            const float4 vb = *(const float4*)(pb + kk * 16);
            const float av[4] = {va.x, va.y, va.z, va.w};
            const float bv[4] = {vb.x, vb.y, vb.z, vb.w};
#pragma unroll
            for (int u = 0; u < 4; ++u) {
                exa[u] = fmaxf(exa[u], m ? av[u] : 0.f);
                faa[u] = fminf(faa[u], m ? av[u] : 1.f);
                exb[u] = fmaxf(exb[u], m ? bv[u] : 0.f);
                fab[u] = fminf(fab[u], m ? bv[u] : 1.f);
            }
        }
#pragma unroll
        for (int u = 0; u < 4; ++u) {
            const int c = c4 + u;
            *(unsigned int*)(lds_in + j * 136 + 32 + 2 * c) = pk2(exa[u], faa[u]);
            *(unsigned int*)(lds_in + j * 136 + 96 + 2 * c) = pk2(exb[u], fab[u]);
        }
    }
    __syncthreads();
    mlp_head<4>(lds_in, lds_w1t, lds_w2t, lds_b1, lds_b2, lds_h,
                out + (size_t)blockIdx.x * 768);
}

// ---------------------------------------------------------------------------
extern "C" void kernel_launch(void* const* d_in, const int* in_sizes, int n_in,
                              void* d_out, int out_size, void* d_ws, size_t ws_size,
                              hipStream_t stream) {
    (void)in_sizes; (void)n_in; (void)out_size;
    const float* x0 = (const float*)d_in[0];
    const float* x1 = (const float*)d_in[1];
    const float* x2 = (const float*)d_in[2];
    const float* x3 = (const float*)d_in[3];
    const float* W1_0 = (const float*)d_in[4];
    const float* b1_0 = (const float*)d_in[5];
    const float* W2_0 = (const float*)d_in[6];
    const float* b2_0 = (const float*)d_in[7];
    const float* W1_1 = (const float*)d_in[8];
    const float* b1_1 = (const float*)d_in[9];
    const float* W2_1 = (const float*)d_in[10];
    const float* b2_1 = (const float*)d_in[11];
    const float* W1_2 = (const float*)d_in[12];
    const float* b1_2 = (const float*)d_in[13];
    const float* W2_2 = (const float*)d_in[14];
    const float* b2_2 = (const float*)d_in[15];
    const float* W1_3 = (const float*)d_in[16];
    const float* b1_3 = (const float*)d_in[17];
    const float* W2_3 = (const float*)d_in[18];
    const float* b2_3 = (const float*)d_in[19];
    float* out = (float*)d_out;

    // Output layout: y0 [0,64) | y1 [64,3136) | y2 [3136,150592) | y3 [150592,...)
    // ws layout (shorts from base):
    //   A fp32 [2*NPAIR] | B [NPAIR] | C [NPAIR] | red3 [NRED3]
    //   | X0 [NX3] | XA [NX3] | XB [NX3]
    const size_t ws_mid  = (size_t)8 * NPAIR + (size_t)2 * NRED3;
    const size_t ws_full = ws_mid + (size_t)6 * NX3;
    if (ws_size >= ws_mid) {
        float* wsA = (float*)d_ws;
        unsigned short* wsB = (unsigned short*)d_ws + 2 * NPAIR;
        unsigned short* wsC = wsB + NPAIR;
        unsigned short* red3 = (unsigned short*)d_ws + 4 * NPAIR;
        phaseA_kernel<<<2304, 256, 0, stream>>>(x2, W1_3, b1_3, wsA, wsB, wsC);
        if (ws_size >= ws_full) {
            unsigned short* X0 = red3 + NRED3;
            unsigned short* XA = X0 + NX3;
            unsigned short* XB = XA + NX3;
            perm3_kernel<<<9216, 192, 0, stream>>>(x3, X0, XA, XB);
            y3_kernel<<<2304, 192, 0, stream>>>(X0, XA, XB, W1_3, W2_3, b2_3,
                                                wsA, wsB, wsC, out + 150592);
        } else {
            y3_gather_kernel<<<2304, 192, 0, stream>>>(x3, W1_3, W2_3, b2_3,
                                                       wsA, wsB, wsC, out + 150592);
        }
        red3_kernel<<<576, 256, 0, stream>>>(x3, red3);
        y2_mlp_kernel<<<192, 192, 0, stream>>>(x1, x2, W1_2, b1_2, W2_2, b2_2,
                                               red3, out + 3136);
    } else {
        y3_fallback_kernel<<<1024, 192, 0, stream>>>(x2, x3, W1_3, b1_3, W2_3, b2_3,
                                                     out + 150592);
        y2_kernel<<<192, 192, 0, stream>>>(x1, x2, x3, W1_2, b1_2, W2_2, b2_2,
                                           out + 3136);
    }
    y01_kernel<<<5, 192, 0, stream>>>(x0, x1, x2, W1_0, b1_0, W2_0, b2_0,
                                      W1_1, b1_1, W2_1, b2_1, out);
}

// Round 9
// 184.021 us; speedup vs baseline: 1.1255x; 1.1255x over previous
//
#include <hip/hip_runtime.h>
#include <hip/hip_bf16.h>

// ---------------------------------------------------------------------------
// LogicLayer fused implementation (MI355X / gfx950)
// B=4, N=48, C=16, H=64; CIN={48,64,128,192}, COUT=16
// Round-9:
//  * y3 software-pipelined: tiles in a block share (b,i) and j=j0+it, so the
//    B pair-term is loop-invariant (loaded once) and next-tile xf/C loads are
//    prefetched before current-tile MFMAs (rotate pattern, 8 tiles/block).
//  * red3 fused into perm3 (block already holds the x3 row; bit-exact fp32
//    reduce from LDS) -- kills the 170MB x3 re-read.
// ---------------------------------------------------------------------------

typedef __bf16 bf16x8 __attribute__((ext_vector_type(8)));
typedef unsigned short us8 __attribute__((ext_vector_type(8)));
typedef float f32x4 __attribute__((ext_vector_type(4)));

#define NPAIR 589824    // 4*48*48*64
#define NRED3 294912    // 4*48*48*32 (shorts)
#define NX3   7077888   // 4*48*48*48*16 (shorts per x3 copy)

__device__ __forceinline__ unsigned short f2bf(float f) {
    __hip_bfloat16 h = __float2bfloat16(f);   // RNE
    return __builtin_bit_cast(unsigned short, h);
}
__device__ __forceinline__ unsigned int pk2(float a, float b) {
    return (unsigned int)f2bf(a) | ((unsigned int)f2bf(b) << 16);
}
__device__ __forceinline__ float bflo(unsigned int u) {
    return __builtin_bit_cast(float, u << 16);
}
__device__ __forceinline__ float bfhi(unsigned int u) {
    return __builtin_bit_cast(float, u & 0xffff0000u);
}
__device__ __forceinline__ float sigmoidf_(float z) {
    return 1.0f / (1.0f + __expf(-z));
}
__device__ __forceinline__ bf16x8 ld_bf8(const unsigned short* p) {
    return __builtin_bit_cast(bf16x8, *(const us8*)p);
}
__device__ __forceinline__ bf16x8 pack8(float4 a, float4 b) {
    us8 u;
    u[0] = f2bf(a.x); u[1] = f2bf(a.y); u[2] = f2bf(a.z); u[3] = f2bf(a.w);
    u[4] = f2bf(b.x); u[5] = f2bf(b.y); u[6] = f2bf(b.z); u[7] = f2bf(b.w);
    return __builtin_bit_cast(bf16x8, u);
}

// ---------------------------------------------------------------------------
// perm3 (+fused red3): x3 (fp32) -> three bf16 copies + masked k-reduction.
// 9216 blocks x 192 thr; block g = (b*48+m1)*48+m2 holds row x3[g,:,:].
// red3 reduce is bit-exact vs the old kernel (same fp32 values & op order).
// ---------------------------------------------------------------------------
__global__ __launch_bounds__(192) void perm3_kernel(
    const float* __restrict__ x3,
    unsigned short* __restrict__ X0, unsigned short* __restrict__ XA,
    unsigned short* __restrict__ XB, unsigned short* __restrict__ red3)
{
    __shared__ float rowf[768];
    const int g = blockIdx.x;                 // (b*48+m1)*48+m2
    const int m2 = g % 48, t1 = g / 48, m1 = t1 % 48, b = t1 / 48;
    const int t = threadIdx.x;
    const int m3 = t >> 2, cq = (t & 3) * 4;
    const float4 v = *(const float4*)(x3 + (size_t)g * 768 + m3 * 16 + cq);
    *(float4*)(rowf + m3 * 16 + cq) = v;
    const uint2 u = make_uint2(pk2(v.x, v.y), pk2(v.z, v.w));
    *(uint2*)(X0 + (size_t)g * 768 + m3 * 16 + cq) = u;
    *(uint2*)(XA + (((size_t)(b * 48 + m1) * 48 + m3) * 48 + m2) * 16 + cq) = u;
    *(uint2*)(XB + (((size_t)(b * 48 + m2) * 48 + m3) * 48 + m1) * 16 + cq) = u;
    __syncthreads();
    if (t < 16) {
        const int c = t;
        float ex = -__builtin_inff(), fa = __builtin_inff();
        const bool mij = (m1 != m2);
#pragma unroll 8
        for (int k = 0; k < 48; ++k) {
            const bool m = mij & (k != m1) & (k != m2);
            const float vv = rowf[k * 16 + c];
            ex = fmaxf(ex, m ? vv : 0.f);
            fa = fminf(fa, m ? vv : 1.f);
        }
        *(unsigned int*)(red3 + (size_t)g * 32 + 2 * c) = pk2(ex, fa);
    }
}

// ---------------------------------------------------------------------------
// Phase A: pair tensors for y3 (verified rounds 4-8).
// ---------------------------------------------------------------------------
__global__ __launch_bounds__(256) void phaseA_kernel(
    const float* __restrict__ x2, const float* __restrict__ W1,
    const float* __restrict__ b1,
    float* __restrict__ wsA, unsigned short* __restrict__ wsB,
    unsigned short* __restrict__ wsC)
{
    __shared__ float xr[4][32];
    const int t = threadIdx.x;
    if (t < 128) {
        const int pr2 = t >> 5, c = t & 31;
        const int gg = blockIdx.x * 4 + pr2;
        const int bb = gg / 2304, pp2 = gg % 2304, P = pp2 / 48, Q = pp2 % 48;
        const float* base = x2 + (size_t)bb * 36864;
        xr[pr2][c] = (c < 16) ? base[(P * 48 + Q) * 16 + c]
                              : base[(Q * 48 + P) * 16 + (c - 16)];
    }
    __syncthreads();
    const int pr = t >> 6, h = t & 63;
    const int g = blockIdx.x * 4 + pr;
    float a = b1[h], bacc = 0.f, cacc = 0.f;
#pragma unroll
    for (int c = 0; c < 16; ++c) {
        const float xpq = xr[pr][c], xqp = xr[pr][16 + c];
        a    += xpq * W1[(  0 + c) * 64 + h] + xqp * W1[( 64 + c) * 64 + h];
        bacc += xpq * W1[( 32 + c) * 64 + h] + xqp * W1[( 96 + c) * 64 + h];
        cacc += xpq * W1[(128 + c) * 64 + h] + xqp * W1[(160 + c) * 64 + h];
    }
    const size_t o = (size_t)g * 64 + h;
    wsA[o] = a;
    wsB[o] = f2bf(bacc);
    wsC[o] = f2bf(cacc);
}

// ---------------------------------------------------------------------------
// y3 (round-9): 1152 blocks x 192 thr, 8 tiles each, software-pipelined.
// Tiles share (b,i); j = j0+it.  B pair-term loaded once; xf + C-term for
// tile it+1 prefetched before tile it's MFMAs (rotate registers).
// ---------------------------------------------------------------------------
#define Y3_TILES 8

__global__ __launch_bounds__(192, 3) void y3_kernel(
    const unsigned short* __restrict__ X0,
    const unsigned short* __restrict__ XA,
    const unsigned short* __restrict__ XB,
    const float* __restrict__ W1, const float* __restrict__ W2,
    const float* __restrict__ b2,
    const float* __restrict__ wsA,
    const unsigned short* __restrict__ wsB,
    const unsigned short* __restrict__ wsC,
    float* __restrict__ out)
{
    __shared__ __align__(16) unsigned short w1t[64 * 104];   // [h][kk], one-time
    const int t = threadIdx.x;
    const int w = t >> 6, lane = t & 63, lr = lane & 15, lg = lane >> 4;

#pragma unroll
    for (int p = 0; p < 16; ++p) {
        const int e = p * 192 + t;
        const int h = e & 63, kk = (e >> 6) * 2;
        const int r0 = 16 + ((kk >> 4) << 5) + (kk & 15);
        *(unsigned int*)(w1t + h * 104 + kk) =
            pk2(W1[r0 * 64 + h], W1[(r0 + 1) * 64 + h]);
    }
    __syncthreads();   // only barrier in the kernel

    bf16x8 w1f[4][3];
#pragma unroll
    for (int n = 0; n < 4; ++n)
#pragma unroll
        for (int ks = 0; ks < 3; ++ks)
            w1f[n][ks] = ld_bf8(w1t + (16 * n + lr) * 104 + 32 * ks + 8 * lg);

    bf16x8 w2f[2];
#pragma unroll
    for (int m = 0; m < 2; ++m) {
        us8 u;
#pragma unroll
        for (int e = 0; e < 8; ++e) {
            const int ch = 16 * (e >> 1) + 4 * lg + 2 * (e & 1) + m;
            u[e] = f2bf(W2[ch * 16 + lr]);
        }
        w2f[m] = __builtin_bit_cast(bf16x8, u);
    }
    const float4 b2v = *(const float4*)(b2 + 4 * lg);
    const int row = 16 * w + lr;
    const int roff = row * 16 + 8 * (lg & 1);
    const bool hi = (lg >> 1) != 0;

    const int g0 = blockIdx.x * Y3_TILES;
    const int b = g0 / 2304, pp = g0 % 2304, i = pp / 48, j0 = pp % 48;

    // B term depends on (b,i,row) only -> loop-invariant, load once
    const size_t baseB = ((size_t)((b * 48 + i) * 48 + row)) * 64 + 4 * lg;
    uint2 Bu[4];
#pragma unroll
    for (int n = 0; n < 4; ++n) Bu[n] = *(const uint2*)(wsB + baseB + 16 * n);

    const size_t rowIJ = ((size_t)(b * 48 + i) * 48) * 768;   // + j*768

    // prologue: tile 0 xf + C loads
    bf16x8 xc0, xc1, xc2;
    uint2 Cu[4];
    {
        const size_t bIJ = rowIJ + (size_t)j0 * 768;
        const size_t bJI = ((size_t)(b * 48 + j0) * 48 + i) * 768;
        xc0 = ld_bf8((hi ? XA + bIJ : X0 + bIJ) + roff);
        xc1 = ld_bf8((hi ? XB + bIJ : X0 + bJI) + roff);
        xc2 = ld_bf8((hi ? XB + bJI : XA + bJI) + roff);
        const size_t baseC = ((size_t)((b * 48 + j0) * 48 + row)) * 64 + 4 * lg;
#pragma unroll
        for (int n = 0; n < 4; ++n) Cu[n] = *(const uint2*)(wsC + baseC + 16 * n);
    }

#pragma unroll
    for (int it = 0; it < Y3_TILES; ++it) {
        const int j = j0 + it;
        // prefetch next tile (xf + C) before this tile's MFMAs
        bf16x8 xn0, xn1, xn2;
        uint2 Cn[4];
        if (it < Y3_TILES - 1) {
            const int jn = j + 1;
            const size_t bIJ = rowIJ + (size_t)jn * 768;
            const size_t bJI = ((size_t)(b * 48 + jn) * 48 + i) * 768;
            xn0 = ld_bf8((hi ? XA + bIJ : X0 + bIJ) + roff);
            xn1 = ld_bf8((hi ? XB + bIJ : X0 + bJI) + roff);
            xn2 = ld_bf8((hi ? XB + bJI : XA + bJI) + roff);
            const size_t baseC = ((size_t)((b * 48 + jn) * 48 + row)) * 64 + 4 * lg;
#pragma unroll
            for (int n = 0; n < 4; ++n) Cn[n] = *(const uint2*)(wsC + baseC + 16 * n);
        }
        // GEMM1 (waits only on xc*, loaded one tile ago)
        f32x4 acc[4];
#pragma unroll
        for (int n = 0; n < 4; ++n) {
            acc[n] = f32x4{0.f, 0.f, 0.f, 0.f};
            acc[n] = __builtin_amdgcn_mfma_f32_16x16x32_bf16(w1f[n][0], xc0, acc[n], 0, 0, 0);
            acc[n] = __builtin_amdgcn_mfma_f32_16x16x32_bf16(w1f[n][1], xc1, acc[n], 0, 0, 0);
            acc[n] = __builtin_amdgcn_mfma_f32_16x16x32_bf16(w1f[n][2], xc2, acc[n], 0, 0, 0);
        }
        // epilogue: + A (in-place, L2-hot) + B (invariant) + C (prefetched)
        const size_t baseA = ((size_t)((b * 48 + i) * 48 + j)) * 64 + 4 * lg;
#pragma unroll
        for (int n = 0; n < 4; ++n) {
            const float4 Au = *(const float4*)(wsA + baseA + 16 * n);
            acc[n][0] = fmaxf(acc[n][0] + Au.x + bflo(Bu[n].x) + bflo(Cu[n].x), 0.f);
            acc[n][1] = fmaxf(acc[n][1] + Au.y + bfhi(Bu[n].x) + bfhi(Cu[n].x), 0.f);
            acc[n][2] = fmaxf(acc[n][2] + Au.z + bflo(Bu[n].y) + bflo(Cu[n].y), 0.f);
            acc[n][3] = fmaxf(acc[n][3] + Au.w + bfhi(Bu[n].y) + bfhi(Cu[n].y), 0.f);
        }
        // GEMM2 (in-register, permuted channels)
        bf16x8 hf[2];
#pragma unroll
        for (int m = 0; m < 2; ++m) {
            us8 u;
#pragma unroll
            for (int e = 0; e < 8; ++e)
                u[e] = f2bf(acc[e >> 1][2 * (e & 1) + m]);
            hf[m] = __builtin_bit_cast(bf16x8, u);
        }
        f32x4 o2 = {0.f, 0.f, 0.f, 0.f};
        o2 = __builtin_amdgcn_mfma_f32_16x16x32_bf16(w2f[0], hf[0], o2, 0, 0, 0);
        o2 = __builtin_amdgcn_mfma_f32_16x16x32_bf16(w2f[1], hf[1], o2, 0, 0, 0);
        float4 ov;
        ov.x = sigmoidf_(o2[0] + b2v.x);
        ov.y = sigmoidf_(o2[1] + b2v.y);
        ov.z = sigmoidf_(o2[2] + b2v.z);
        ov.w = sigmoidf_(o2[3] + b2v.w);
        *(float4*)(out + (size_t)(g0 + it) * 768 + row * 16 + 4 * lg) = ov;
        // rotate
        if (it < Y3_TILES - 1) {
            xc0 = xn0; xc1 = xn1; xc2 = xn2;
#pragma unroll
            for (int n = 0; n < 4; ++n) Cu[n] = Cn[n];
        }
    }
}

// ---------------------------------------------------------------------------
// y3 gather version (round-6/8 verified) — middle-tier fallback.
// ---------------------------------------------------------------------------
__global__ __launch_bounds__(192, 3) void y3_gather_kernel(
    const float* __restrict__ x3,
    const float* __restrict__ W1, const float* __restrict__ W2,
    const float* __restrict__ b2,
    const float* __restrict__ wsA,
    const unsigned short* __restrict__ wsB,
    const unsigned short* __restrict__ wsC,
    float* __restrict__ out)
{
    __shared__ __align__(16) unsigned short w1t[64 * 104];
    const int t = threadIdx.x;
    const int w = t >> 6, lane = t & 63, lr = lane & 15, lg = lane >> 4;
#pragma unroll
    for (int p = 0; p < 16; ++p) {
        const int e = p * 192 + t;
        const int h = e & 63, kk = (e >> 6) * 2;
        const int r0 = 16 + ((kk >> 4) << 5) + (kk & 15);
        *(unsigned int*)(w1t + h * 104 + kk) =
            pk2(W1[r0 * 64 + h], W1[(r0 + 1) * 64 + h]);
    }
    __syncthreads();
    bf16x8 w1f[4][3];
#pragma unroll
    for (int n = 0; n < 4; ++n)
#pragma unroll
        for (int ks = 0; ks < 3; ++ks)
            w1f[n][ks] = ld_bf8(w1t + (16 * n + lr) * 104 + 32 * ks + 8 * lg);
    bf16x8 w2f[2];
#pragma unroll
    for (int m = 0; m < 2; ++m) {
        us8 u;
#pragma unroll
        for (int e = 0; e < 8; ++e) {
            const int ch = 16 * (e >> 1) + 4 * lg + 2 * (e & 1) + m;
            u[e] = f2bf(W2[ch * 16 + lr]);
        }
        w2f[m] = __builtin_bit_cast(bf16x8, u);
    }
    const float4 b2v = *(const float4*)(b2 + 4 * lg);
    const int row = 16 * w + lr;
    const int c0 = 8 * (lg & 1);
    const bool hi = (lg >> 1) != 0;
    for (int it = 0; it < 4; ++it) {
        const int g = blockIdx.x * 4 + it;
        const int b = g / 2304, pp = g % 2304, i = pp / 48, j = pp % 48;
        const float* xb3 = x3 + (size_t)b * 1769472;
        const int sb0 = i * 36864 + j * 768 + row * 16;
        const int sb1 = i * 36864 + row * 768 + j * 16;
        const int sb2 = j * 36864 + i * 768 + row * 16;
        const int sb3 = row * 36864 + i * 768 + j * 16;
        const int sb4 = j * 36864 + row * 768 + i * 16;
        const int sb5 = row * 36864 + j * 768 + i * 16;
        const float* p0 = xb3 + (hi ? sb1 : sb0) + c0;
        const float* p1 = xb3 + (hi ? sb3 : sb2) + c0;
        const float* p2 = xb3 + (hi ? sb5 : sb4) + c0;
        const bf16x8 xf0 = pack8(*(const float4*)p0, *(const float4*)(p0 + 4));
        const bf16x8 xf1 = pack8(*(const float4*)p1, *(const float4*)(p1 + 4));
        const bf16x8 xf2 = pack8(*(const float4*)p2, *(const float4*)(p2 + 4));
        f32x4 acc[4];
#pragma unroll
        for (int n = 0; n < 4; ++n) {
            acc[n] = f32x4{0.f, 0.f, 0.f, 0.f};
            acc[n] = __builtin_amdgcn_mfma_f32_16x16x32_bf16(w1f[n][0], xf0, acc[n], 0, 0, 0);
            acc[n] = __builtin_amdgcn_mfma_f32_16x16x32_bf16(w1f[n][1], xf1, acc[n], 0, 0, 0);
            acc[n] = __builtin_amdgcn_mfma_f32_16x16x32_bf16(w1f[n][2], xf2, acc[n], 0, 0, 0);
        }
        const size_t baseB = ((size_t)((b * 48 + i) * 48 + row)) * 64 + 4 * lg;
        const size_t baseC = ((size_t)((b * 48 + j) * 48 + row)) * 64 + 4 * lg;
        const size_t baseA = ((size_t)((b * 48 + i) * 48 + j)) * 64 + 4 * lg;
#pragma unroll
        for (int n = 0; n < 4; ++n) {
            const uint2 Bu = *(const uint2*)(wsB + baseB + 16 * n);
            const uint2 Cu = *(const uint2*)(wsC + baseC + 16 * n);
            const float4 Au = *(const float4*)(wsA + baseA + 16 * n);
            acc[n][0] = fmaxf(acc[n][0] + Au.x + bflo(Bu.x) + bflo(Cu.x), 0.f);
            acc[n][1] = fmaxf(acc[n][1] + Au.y + bfhi(Bu.x) + bfhi(Cu.x), 0.f);
            acc[n][2] = fmaxf(acc[n][2] + Au.z + bflo(Bu.y) + bflo(Cu.y), 0.f);
            acc[n][3] = fmaxf(acc[n][3] + Au.w + bfhi(Bu.y) + bfhi(Cu.y), 0.f);
        }
        bf16x8 hf[2];
#pragma unroll
        for (int m = 0; m < 2; ++m) {
            us8 u;
#pragma unroll
            for (int e = 0; e < 8; ++e)
                u[e] = f2bf(acc[e >> 1][2 * (e & 1) + m]);
            hf[m] = __builtin_bit_cast(bf16x8, u);
        }
        f32x4 o2 = {0.f, 0.f, 0.f, 0.f};
        o2 = __builtin_amdgcn_mfma_f32_16x16x32_bf16(w2f[0], hf[0], o2, 0, 0, 0);
        o2 = __builtin_amdgcn_mfma_f32_16x16x32_bf16(w2f[1], hf[1], o2, 0, 0, 0);
        float4 ov;
        ov.x = sigmoidf_(o2[0] + b2v.x);
        ov.y = sigmoidf_(o2[1] + b2v.y);
        ov.z = sigmoidf_(o2[2] + b2v.z);
        ov.w = sigmoidf_(o2[3] + b2v.w);
        *(float4*)(out + (size_t)g * 768 + row * 16 + 4 * lg) = ov;
    }
}

// ---------------------------------------------------------------------------
// red3 standalone (mid-tier fallback only; full path fuses it into perm3)
// ---------------------------------------------------------------------------
__global__ __launch_bounds__(256) void red3_kernel(
    const float* __restrict__ x3, unsigned short* __restrict__ red3)
{
    const int slot = blockIdx.x * 256 + threadIdx.x;
    const int c = slot & 15;
    const int q = slot >> 4;          // pi*48 + j, pi = b*48+i
    const int j = q % 48, pi = q / 48, i = pi % 48;
    const float* p = x3 + (size_t)q * 768 + c;
    float ex = -__builtin_inff(), fa = __builtin_inff();
    const bool mij = (i != j);
#pragma unroll 8
    for (int k = 0; k < 48; ++k) {
        const bool m = mij & (k != i) & (k != j);
        const float v = p[k * 16];
        ex = fmaxf(ex, m ? v : 0.f);
        fa = fminf(fa, m ? v : 1.f);
    }
    *(unsigned int*)(red3 + (size_t)q * 32 + 2 * c) = pk2(ex, fa);
}

// ---------------------------------------------------------------------------
// y2 MLP (verified rounds 5-8)
// ---------------------------------------------------------------------------
__global__ __launch_bounds__(192, 3) void y2_mlp_kernel(
    const float* __restrict__ x1, const float* __restrict__ x2,
    const float* __restrict__ W1, const float* __restrict__ b1,
    const float* __restrict__ W2, const float* __restrict__ b2,
    const unsigned short* __restrict__ red3, float* __restrict__ out)
{
    __shared__ __align__(16) unsigned short w1t[64 * 136];
    const int t = threadIdx.x;
    const int w = t >> 6, lane = t & 63, lr = lane & 15, lg = lane >> 4;

#pragma unroll
    for (int p = 0; p < 22; ++p) {
        const int e = p * 192 + t;
        if (e < 4096) {
            const int h = e & 63, k2 = e >> 6;
            *(unsigned int*)(w1t + h * 136 + 2 * k2) =
                pk2(W1[(2 * k2) * 64 + h], W1[(2 * k2 + 1) * 64 + h]);
        }
    }
    __syncthreads();

    bf16x8 w1f[4][4];
#pragma unroll
    for (int n = 0; n < 4; ++n)
#pragma unroll
        for (int ks = 0; ks < 4; ++ks)
            w1f[n][ks] = ld_bf8(w1t + (16 * n + lr) * 136 + 32 * ks + 8 * lg);

    bf16x8 w2f[2];
#pragma unroll
    for (int m = 0; m < 2; ++m) {
        us8 u;
#pragma unroll
        for (int e = 0; e < 8; ++e) {
            const int ch = 16 * (e >> 1) + 4 * lg + 2 * (e & 1) + m;
            u[e] = f2bf(W2[ch * 16 + lr]);
        }
        w2f[m] = __builtin_bit_cast(bf16x8, u);
    }
    float4 b1v[4];
#pragma unroll
    for (int n = 0; n < 4; ++n) b1v[n] = *(const float4*)(b1 + 16 * n + 4 * lg);
    const float4 b2v = *(const float4*)(b2 + 4 * lg);

    const int bq = blockIdx.x;                 // b*48 + i
    const int b = bq / 48, i = bq % 48;
    const float* x2b = x2 + (size_t)b * 36864;
    const int row = 16 * w + lr;               // = j
    const int j = row;
    const int c0 = 8 * (lg & 1);
    const bool hi = (lg >> 1) != 0;

    const float* a0 = hi ? (x2b + (i * 48 + j) * 16 + c0) : (x1 + (b * 48 + i) * 16 + c0);
    const float* a2 = hi ? (x2b + (j * 48 + i) * 16 + c0) : (x1 + (b * 48 + j) * 16 + c0);
    const unsigned short* r1 = red3 + ((size_t)(b * 48 + i) * 48 + j) * 32 + (hi ? 16 : 0) + c0;
    const unsigned short* r3 = red3 + ((size_t)(b * 48 + j) * 48 + i) * 32 + (hi ? 16 : 0) + c0;

    const bf16x8 xf0 = pack8(*(const float4*)a0, *(const float4*)(a0 + 4));
    const bf16x8 xf1 = ld_bf8(r1);
    const bf16x8 xf2 = pack8(*(const float4*)a2, *(const float4*)(a2 + 4));
    const bf16x8 xf3 = ld_bf8(r3);

    f32x4 acc[4];
#pragma unroll
    for (int n = 0; n < 4; ++n) {
        acc[n] = f32x4{0.f, 0.f, 0.f, 0.f};
        acc[n] = __builtin_amdgcn_mfma_f32_16x16x32_bf16(w1f[n][0], xf0, acc[n], 0, 0, 0);
        acc[n] = __builtin_amdgcn_mfma_f32_16x16x32_bf16(w1f[n][1], xf1, acc[n], 0, 0, 0);
        acc[n] = __builtin_amdgcn_mfma_f32_16x16x32_bf16(w1f[n][2], xf2, acc[n], 0, 0, 0);
        acc[n] = __builtin_amdgcn_mfma_f32_16x16x32_bf16(w1f[n][3], xf3, acc[n], 0, 0, 0);
    }
#pragma unroll
    for (int n = 0; n < 4; ++n) {
        acc[n][0] = fmaxf(acc[n][0] + b1v[n].x, 0.f);
        acc[n][1] = fmaxf(acc[n][1] + b1v[n].y, 0.f);
        acc[n][2] = fmaxf(acc[n][2] + b1v[n].z, 0.f);
        acc[n][3] = fmaxf(acc[n][3] + b1v[n].w, 0.f);
    }
    bf16x8 hf[2];
#pragma unroll
    for (int m = 0; m < 2; ++m) {
        us8 u;
#pragma unroll
        for (int e = 0; e < 8; ++e)
            u[e] = f2bf(acc[e >> 1][2 * (e & 1) + m]);
        hf[m] = __builtin_bit_cast(bf16x8, u);
    }
    f32x4 o2 = {0.f, 0.f, 0.f, 0.f};
    o2 = __builtin_amdgcn_mfma_f32_16x16x32_bf16(w2f[0], hf[0], o2, 0, 0, 0);
    o2 = __builtin_amdgcn_mfma_f32_16x16x32_bf16(w2f[1], hf[1], o2, 0, 0, 0);
    float4 ov;
    ov.x = sigmoidf_(o2[0] + b2v.x);
    ov.y = sigmoidf_(o2[1] + b2v.y);
    ov.z = sigmoidf_(o2[2] + b2v.z);
    ov.w = sigmoidf_(o2[3] + b2v.w);
    *(float4*)(out + ((size_t)bq * 48 + row) * 16 + 4 * lg) = ov;
}

// ---------------------------------------------------------------------------
// y0 + y1 (verified round 6/8)
// ---------------------------------------------------------------------------
__global__ __launch_bounds__(192, 1) void y01_kernel(
    const float* __restrict__ x0, const float* __restrict__ x1,
    const float* __restrict__ x2,
    const float* __restrict__ W1_0, const float* __restrict__ b1_0,
    const float* __restrict__ W2_0, const float* __restrict__ b2_0,
    const float* __restrict__ W1_1, const float* __restrict__ b1_1,
    const float* __restrict__ W2_1, const float* __restrict__ b2_1,
    float* __restrict__ out)
{
    const int t = threadIdx.x;
    if (blockIdx.x < 4) {
        __shared__ __align__(16) unsigned short w1t[64 * 72];
        __shared__ __align__(16) unsigned short red2l[48 * 32];
        const int b = blockIdx.x;
#pragma unroll
        for (int p = 0; p < 11; ++p) {
            const int e = p * 192 + t;
            if (e < 2048) {
                const int h = e & 63, k2 = e >> 6;
                *(unsigned int*)(w1t + h * 72 + 2 * k2) =
                    pk2(W1_1[(2 * k2) * 64 + h], W1_1[(2 * k2 + 1) * 64 + h]);
            }
        }
        const float* x2b = x2 + (size_t)b * 36864;
#pragma unroll
        for (int s4 = 0; s4 < 4; ++s4) {
            const int s = t + 192 * s4;            // 0..767
            const int i = s >> 4, c = s & 15;
            const float* p = x2b + i * 768 + c;
            float ex = -__builtin_inff(), fa = __builtin_inff();
#pragma unroll 8
            for (int jj = 0; jj < 48; ++jj) {
                const bool m = (jj != i);
                const float v = p[jj * 16];
                ex = fmaxf(ex, m ? v : 0.f);
                fa = fminf(fa, m ? v : 1.f);
            }
            *(unsigned int*)(red2l + i * 32 + 2 * c) = pk2(ex, fa);
        }
        __syncthreads();

        const int w = t >> 6, lane = t & 63, lr = lane & 15, lg = lane >> 4;
        const int i = 16 * w + lr;
        const int rho = b * 48 + i;
        bf16x8 w1f[4][2];
#pragma unroll
        for (int n = 0; n < 4; ++n)
#pragma unroll
            for (int ks = 0; ks < 2; ++ks)
                w1f[n][ks] = ld_bf8(w1t + (16 * n + lr) * 72 + 32 * ks + 8 * lg);
        bf16x8 w2f[2];
#pragma unroll
        for (int m = 0; m < 2; ++m) {
            us8 u;
#pragma unroll
            for (int e = 0; e < 8; ++e) {
                const int ch = 16 * (e >> 1) + 4 * lg + 2 * (e & 1) + m;
                u[e] = f2bf(W2_1[ch * 16 + lr]);
            }
            w2f[m] = __builtin_bit_cast(bf16x8, u);
        }
        float4 b1v[4];
#pragma unroll
        for (int n = 0; n < 4; ++n) b1v[n] = *(const float4*)(b1_1 + 16 * n + 4 * lg);
        const float4 b2v = *(const float4*)(b2_1 + 4 * lg);

        const int c0 = 8 * (lg & 1);
        const float* a0 = (lg < 2) ? (x0 + b * 16 + c0) : (x1 + rho * 16 + c0);
        const bf16x8 xf0 = pack8(*(const float4*)a0, *(const float4*)(a0 + 4));
        const bf16x8 xf1 = ld_bf8(red2l + i * 32 + 8 * lg);

        f32x4 acc[4];
#pragma unroll
        for (int n = 0; n < 4; ++n) {
            acc[n] = f32x4{0.f, 0.f, 0.f, 0.f};
            acc[n] = __builtin_amdgcn_mfma_f32_16x16x32_bf16(w1f[n][0], xf0, acc[n], 0, 0, 0);
            acc[n] = __builtin_amdgcn_mfma_f32_16x16x32_bf16(w1f[n][1], xf1, acc[n], 0, 0, 0);
        }
#pragma unroll
        for (int n = 0; n < 4; ++n) {
            acc[n][0] = fmaxf(acc[n][0] + b1v[n].x, 0.f);
            acc[n][1] = fmaxf(acc[n][1] + b1v[n].y, 0.f);
            acc[n][2] = fmaxf(acc[n][2] + b1v[n].z, 0.f);
            acc[n][3] = fmaxf(acc[n][3] + b1v[n].w, 0.f);
        }
        bf16x8 hf[2];
#pragma unroll
        for (int m = 0; m < 2; ++m) {
            us8 u;
#pragma unroll
            for (int e = 0; e < 8; ++e)
                u[e] = f2bf(acc[e >> 1][2 * (e & 1) + m]);
            hf[m] = __builtin_bit_cast(bf16x8, u);
        }
        f32x4 o2 = {0.f, 0.f, 0.f, 0.f};
        o2 = __builtin_amdgcn_mfma_f32_16x16x32_bf16(w2f[0], hf[0], o2, 0, 0, 0);
        o2 = __builtin_amdgcn_mfma_f32_16x16x32_bf16(w2f[1], hf[1], o2, 0, 0, 0);
        float4 ov;
        ov.x = sigmoidf_(o2[0] + b2v.x);
        ov.y = sigmoidf_(o2[1] + b2v.y);
        ov.z = sigmoidf_(o2[2] + b2v.z);
        ov.w = sigmoidf_(o2[3] + b2v.w);
        *(float4*)(out + 64 + (size_t)rho * 16 + 4 * lg) = ov;
    } else {
        __shared__ float t0l[4][56];
        __shared__ float hl[4][72];
        if (t < 64) {
            const int b = t >> 4, c = t & 15;
            const float* p = x1 + b * 768 + c;
            float ex = -__builtin_inff(), fa = __builtin_inff();
#pragma unroll 8
            for (int n = 0; n < 48; ++n) {
                const float v = p[n * 16];
                ex = fmaxf(ex, v);
                fa = fminf(fa, v);
            }
            t0l[b][c] = x0[b * 16 + c];
            t0l[b][16 + 2 * c] = ex;
            t0l[b][17 + 2 * c] = fa;
        }
        __syncthreads();
        if (t < 64) {
            const int h = t;
            float ac0 = b1_0[h], ac1 = ac0, ac2 = ac0, ac3 = ac0;
#pragma unroll
            for (int c = 0; c < 48; ++c) {
                const float wv = W1_0[c * 64 + h];
                ac0 = fmaf(t0l[0][c], wv, ac0);
                ac1 = fmaf(t0l[1][c], wv, ac1);
                ac2 = fmaf(t0l[2][c], wv, ac2);
                ac3 = fmaf(t0l[3][c], wv, ac3);
            }
            hl[0][h] = fmaxf(ac0, 0.f);
            hl[1][h] = fmaxf(ac1, 0.f);
            hl[2][h] = fmaxf(ac2, 0.f);
            hl[3][h] = fmaxf(ac3, 0.f);
        }
        __syncthreads();
        if (t < 64) {
            const int b = t >> 4, o = t & 15;
            float a = b2_0[o];
#pragma unroll
            for (int h = 0; h < 64; ++h)
                a = fmaf(hl[b][h], W2_0[h * 16 + o], a);
            out[b * 16 + o] = sigmoidf_(a);
        }
    }
}

// ---------------------------------------------------------------------------
// Lowest-tier fallbacks (verified round 1/4), used only if ws too small.
// ---------------------------------------------------------------------------
template <int NK>
__device__ __forceinline__ void mlp_head(
    const unsigned short* lds_in, const unsigned short* lds_w1t,
    const unsigned short* lds_w2t, const float* lds_b1, const float* lds_b2,
    unsigned short* lds_h, float* outp)
{
    constexpr int S = NK * 32 + 8;
    const int t = threadIdx.x;
    const int w = t >> 6, lr = t & 15, lg = (t >> 4) & 3;
    f32x4 acc0 = {0.f, 0.f, 0.f, 0.f};
    f32x4 acc1 = acc0, acc2 = acc0, acc3 = acc0;
    const unsigned short* pa = lds_in + (16 * w + lr) * S + lg * 8;
    const unsigned short* pb = lds_w1t + lr * S + lg * 8;
#pragma unroll
    for (int ks = 0; ks < NK; ++ks) {
        bf16x8 a = ld_bf8(pa + ks * 32);
        acc0 = __builtin_amdgcn_mfma_f32_16x16x32_bf16(a, ld_bf8(pb + 0 * 16 * S + ks * 32), acc0, 0, 0, 0);
        acc1 = __builtin_amdgcn_mfma_f32_16x16x32_bf16(a, ld_bf8(pb + 1 * 16 * S + ks * 32), acc1, 0, 0, 0);
        acc2 = __builtin_amdgcn_mfma_f32_16x16x32_bf16(a, ld_bf8(pb + 2 * 16 * S + ks * 32), acc2, 0, 0, 0);
        acc3 = __builtin_amdgcn_mfma_f32_16x16x32_bf16(a, ld_bf8(pb + 3 * 16 * S + ks * 32), acc3, 0, 0, 0);
    }
    const int hrow = 16 * w + lg * 4;
#pragma unroll
    for (int r = 0; r < 4; ++r) {
        lds_h[(hrow + r) * 72 +  0 + lr] = f2bf(fmaxf(acc0[r] + lds_b1[ 0 + lr], 0.f));
        lds_h[(hrow + r) * 72 + 16 + lr] = f2bf(fmaxf(acc1[r] + lds_b1[16 + lr], 0.f));
        lds_h[(hrow + r) * 72 + 32 + lr] = f2bf(fmaxf(acc2[r] + lds_b1[32 + lr], 0.f));
        lds_h[(hrow + r) * 72 + 48 + lr] = f2bf(fmaxf(acc3[r] + lds_b1[48 + lr], 0.f));
    }
    __syncthreads();
    f32x4 o = {0.f, 0.f, 0.f, 0.f};
#pragma unroll
    for (int ks = 0; ks < 2; ++ks) {
        bf16x8 a = ld_bf8(lds_h + (16 * w + lr) * 72 + ks * 32 + lg * 8);
        bf16x8 b = ld_bf8(lds_w2t + lr * 72 + ks * 32 + lg * 8);
        o = __builtin_amdgcn_mfma_f32_16x16x32_bf16(a, b, o, 0, 0, 0);
    }
    const float b2v = lds_b2[lr];
#pragma unroll
    for (int r = 0; r < 4; ++r)
        outp[(hrow + r) * 16 + lr] = sigmoidf_(o[r] + b2v);
}

__global__ __launch_bounds__(192) void y3_fallback_kernel(
    const float* __restrict__ x2, const float* __restrict__ x3,
    const float* __restrict__ W1, const float* __restrict__ b1,
    const float* __restrict__ W2, const float* __restrict__ b2,
    float* __restrict__ out)
{
    __shared__ __align__(16) unsigned short lds_in[48 * 200];
    __shared__ __align__(16) unsigned short lds_w1t[64 * 200];
    __shared__ __align__(16) unsigned short lds_w2t[16 * 72];
    __shared__ __align__(16) unsigned short lds_h[48 * 72];
    __shared__ float lds_b1[64];
    __shared__ float lds_b2[16];
    const int t = threadIdx.x;
#pragma unroll 4
    for (int p = 0; p < 32; ++p) {
        int e = p * 192 + t;
        int h = e & 63, c2 = e >> 6;
        *(unsigned int*)(lds_w1t + h * 200 + 2 * c2) =
            pk2(W1[(2 * c2) * 64 + h], W1[(2 * c2 + 1) * 64 + h]);
    }
    for (int p = 0; p < 3; ++p) {
        int e = p * 192 + t;
        if (e < 512) {
            int n = e & 15, k2 = e >> 4;
            *(unsigned int*)(lds_w2t + n * 72 + 2 * k2) =
                pk2(W2[(2 * k2) * 16 + n], W2[(2 * k2 + 1) * 16 + n]);
        }
    }
    if (t < 64) lds_b1[t] = b1[t];
    if (t < 16) lds_b2[t] = b2[t];
    const int k = t >> 2, c4 = (t & 3) * 4;
#define STAGE3(PTR, BASE, KSTR, CH) do {                                       \
        const float4 v = *(const float4*)((PTR) + (BASE) + k * (KSTR) + c4);   \
        *(uint2*)(lds_in + k * 200 + (CH) + c4) =                              \
            make_uint2(pk2(v.x, v.y), pk2(v.z, v.w));                          \
    } while (0)
    for (int it = 0; it < 9; ++it) {
        const int g = blockIdx.x * 9 + it;
        const int b = g / 2304, rg = g % 2304, i = rg / 48, j = rg % 48;
        const float* xb2 = x2 + b * 36864;
        const float* xb3 = x3 + b * 1769472;
        __syncthreads();
        STAGE3(xb2, i * 768 + j * 16, 0,       0);
        STAGE3(xb3, i * 36864 + j * 768, 16,   16);
        STAGE3(xb2, i * 768, 16,               32);
        STAGE3(xb3, i * 36864 + j * 16, 768,   48);
        STAGE3(xb2, j * 768 + i * 16, 0,       64);
        STAGE3(xb3, j * 36864 + i * 768, 16,   80);
        STAGE3(xb2, i * 16, 768,               96);
        STAGE3(xb3, i * 768 + j * 16, 36864,   112);
        STAGE3(xb2, j * 768, 16,               128);
        STAGE3(xb3, j * 36864 + i * 16, 768,   144);
        STAGE3(xb2, j * 16, 768,               160);
        STAGE3(xb3, j * 768 + i * 16, 36864,   176);
        __syncthreads();
        mlp_head<6>(lds_in, lds_w1t, lds_w2t, lds_b1, lds_b2, lds_h,
                    out + (size_t)g * 768);
    }
#undef STAGE3
}

__global__ __launch_bounds__(192) void y2_kernel(
    const float* __restrict__ x1, const float* __restrict__ x2,
    const float* __restrict__ x3,
    const float* __restrict__ W1, const float* __restrict__ b1,
    const float* __restrict__ W2, const float* __restrict__ b2,
    float* __restrict__ out)
{
    __shared__ __align__(16) unsigned short lds_in[48 * 136];
    __shared__ __align__(16) unsigned short lds_w1t[64 * 136];
    __shared__ __align__(16) unsigned short lds_w2t[16 * 72];
    __shared__ __align__(16) unsigned short lds_h[48 * 72];
    __shared__ float lds_b1[64];
    __shared__ float lds_b2[16];
    const int t = threadIdx.x;
    const int b = blockIdx.x / 48, i = blockIdx.x % 48;
#pragma unroll 2
    for (int p = 0; p < 22; ++p) {
        int e = p * 192 + t;
        if (e < 4096) {
            int h = e & 63, c2 = e >> 6;
            *(unsigned int*)(lds_w1t + h * 136 + 2 * c2) =
                pk2(W1[(2 * c2) * 64 + h], W1[(2 * c2 + 1) * 64 + h]);
        }
    }
    for (int p = 0; p < 3; ++p) {
        int e = p * 192 + t;
        if (e < 512) {
            int n = e & 15, k2 = e >> 4;
            *(unsigned int*)(lds_w2t + n * 72 + 2 * k2) =
                pk2(W2[(2 * k2) * 16 + n], W2[(2 * k2 + 1) * 16 + n]);
        }
    }
    if (t < 64) lds_b1[t] = b1[t];
    if (t < 16) lds_b2[t] = b2[t];
    const int j = t >> 2, c4 = (t & 3) * 4;
    const float* xb2 = x2 + b * 36864;
#define STAGE2(PTR, BASE, JSTR, CH) do {                                       \
        const float4 v = *(const float4*)((PTR) + (BASE) + j * (JSTR) + c4);   \
        *(uint2*)(lds_in + j * 136 + (CH) + c4) =                              \
            make_uint2(pk2(v.x, v.y), pk2(v.z, v.w));                          \
    } while (0)
    STAGE2(x1, b * 768 + i * 16, 0,  0);
    STAGE2(xb2, i * 768, 16,         16);
    STAGE2(x1, b * 768, 16,          64);
    STAGE2(xb2, i * 16, 768,         80);
#undef STAGE2
    {
        const float* pa = x3 + b * 1769472 + (i * 48 + j) * 768 + c4;
        const float* pb = x3 + b * 1769472 + (j * 48 + i) * 768 + c4;
        float exa[4], faa[4], exb[4], fab[4];
#pragma unroll
        for (int u = 0; u < 4; ++u) {
            exa[u] = -__builtin_inff(); faa[u] = __builtin_inff();
            exb[u] = -__builtin_inff(); fab[u] = __builtin_inff();
        }
        for (int kk = 0; kk < 48; ++kk) {
            const bool m = (i != j) & (i != kk) & (j != kk);
            const float4 va = *(const float4*)(pa + kk * 16);
            const float4 vb = *(const float4*)(pb + kk * 16);
            const float av[4] = {va.x, va.y, va.z, va.w};
            const float bv[4] = {vb.x, vb.y, vb.z, vb.w};
#pragma unroll
            for (int u = 0; u < 4; ++u) {
                exa[u] = fmaxf(exa[u], m ? av[u] : 0.f);
                faa[u] = fminf(faa[u], m ? av[u] : 1.f);
                exb[u] = fmaxf(exb[u], m ? bv[u] : 0.f);
                fab[u] = fminf(fab[u], m ? bv[u] : 1.f);
            }
        }
#pragma unroll
        for (int u = 0; u < 4; ++u) {
            const int c = c4 + u;
            *(unsigned int*)(lds_in + j * 136 + 32 + 2 * c) = pk2(exa[u], faa[u]);
            *(unsigned int*)(lds_in + j * 136 + 96 + 2 * c) = pk2(exb[u], fab[u]);
        }
    }
    __syncthreads();
    mlp_head<4>(lds_in, lds_w1t, lds_w2t, lds_b1, lds_b2, lds_h,
                out + (size_t)blockIdx.x * 768);
}

// ---------------------------------------------------------------------------
extern "C" void kernel_launch(void* const* d_in, const int* in_sizes, int n_in,
                              void* d_out, int out_size, void* d_ws, size_t ws_size,
                              hipStream_t stream) {
    (void)in_sizes; (void)n_in; (void)out_size;
    const float* x0 = (const float*)d_in[0];
    const float* x1 = (const float*)d_in[1];
    const float* x2 = (const float*)d_in[2];
    const float* x3 = (const float*)d_in[3];
    const float* W1_0 = (const float*)d_in[4];
    const float* b1_0 = (const float*)d_in[5];
    const float* W2_0 = (const float*)d_in[6];
    const float* b2_0 = (const float*)d_in[7];
    const float* W1_1 = (const float*)d_in[8];
    const float* b1_1 = (const float*)d_in[9];
    const float* W2_1 = (const float*)d_in[10];
    const float* b2_1 = (const float*)d_in[11];
    const float* W1_2 = (const float*)d_in[12];
    const float* b1_2 = (const float*)d_in[13];
    const float* W2_2 = (const float*)d_in[14];
    const float* b2_2 = (const float*)d_in[15];
    const float* W1_3 = (const float*)d_in[16];
    const float* b1_3 = (const float*)d_in[17];
    const float* W2_3 = (const float*)d_in[18];
    const float* b2_3 = (const float*)d_in[19];
    float* out = (float*)d_out;

    // Output layout: y0 [0,64) | y1 [64,3136) | y2 [3136,150592) | y3 [150592,...)
    // ws layout (shorts from base):
    //   A fp32 [2*NPAIR] | B [NPAIR] | C [NPAIR] | red3 [NRED3]
    //   | X0 [NX3] | XA [NX3] | XB [NX3]
    const size_t ws_mid  = (size_t)8 * NPAIR + (size_t)2 * NRED3;
    const size_t ws_full = ws_mid + (size_t)6 * NX3;
    if (ws_size >= ws_mid) {
        float* wsA = (float*)d_ws;
        unsigned short* wsB = (unsigned short*)d_ws + 2 * NPAIR;
        unsigned short* wsC = wsB + NPAIR;
        unsigned short* red3 = (unsigned short*)d_ws + 4 * NPAIR;
        phaseA_kernel<<<2304, 256, 0, stream>>>(x2, W1_3, b1_3, wsA, wsB, wsC);
        if (ws_size >= ws_full) {
            unsigned short* X0 = red3 + NRED3;
            unsigned short* XA = X0 + NX3;
            unsigned short* XB = XA + NX3;
            perm3_kernel<<<9216, 192, 0, stream>>>(x3, X0, XA, XB, red3);
            y3_kernel<<<9216 / Y3_TILES, 192, 0, stream>>>(
                X0, XA, XB, W1_3, W2_3, b2_3, wsA, wsB, wsC, out + 150592);
        } else {
            y3_gather_kernel<<<2304, 192, 0, stream>>>(x3, W1_3, W2_3, b2_3,
                                                       wsA, wsB, wsC, out + 150592);
            red3_kernel<<<576, 256, 0, stream>>>(x3, red3);
        }
        y2_mlp_kernel<<<192, 192, 0, stream>>>(x1, x2, W1_2, b1_2, W2_2, b2_2,
                                               red3, out + 3136);
    } else {
        y3_fallback_kernel<<<1024, 192, 0, stream>>>(x2, x3, W1_3, b1_3, W2_3, b2_3,
                                                     out + 150592);
        y2_kernel<<<192, 192, 0, stream>>>(x1, x2, x3, W1_2, b1_2, W2_2, b2_2,
                                           out + 3136);
    }
    y01_kernel<<<5, 192, 0, stream>>>(x0, x1, x2, W1_0, b1_0, W2_0, b2_0,
                                      W1_1, b1_1, W2_1, b2_1, out);
}

// Round 10
// 166.751 us; speedup vs baseline: 1.2421x; 1.1036x over previous
//
#include <hip/hip_runtime.h>
#include <hip/hip_bf16.h>

// ---------------------------------------------------------------------------
// LogicLayer fused implementation (MI355X / gfx950)
// B=4, N=48, C=16, H=64; CIN={48,64,128,192}, COUT=16
// Round-10: collapse 5 kernels -> 2 fused launches.
//   K1 pre_kernel  = phaseA (blocks<2304) || perm3+red3 (blocks>=2304)
//   K2 main_kernel = y3 (<1152) || y2 (1152..1343) || y01 (1344..1348)
// y3: A-term now prefetched with C-term (was the only latency-exposed load).
// perm3's red3 tail parallelized 16->192 threads (two-stage LDS reduce).
// All bodies verbatim from verified rounds 6-9.
// ---------------------------------------------------------------------------

typedef __bf16 bf16x8 __attribute__((ext_vector_type(8)));
typedef unsigned short us8 __attribute__((ext_vector_type(8)));
typedef float f32x4 __attribute__((ext_vector_type(4)));

#define NPAIR 589824    // 4*48*48*64
#define NRED3 294912    // 4*48*48*32 (shorts)
#define NX3   7077888   // 4*48*48*48*16 (shorts per x3 copy)
#define Y3_TILES 8

__device__ __forceinline__ unsigned short f2bf(float f) {
    __hip_bfloat16 h = __float2bfloat16(f);   // RNE
    return __builtin_bit_cast(unsigned short, h);
}
__device__ __forceinline__ unsigned int pk2(float a, float b) {
    return (unsigned int)f2bf(a) | ((unsigned int)f2bf(b) << 16);
}
__device__ __forceinline__ float bflo(unsigned int u) {
    return __builtin_bit_cast(float, u << 16);
}
__device__ __forceinline__ float bfhi(unsigned int u) {
    return __builtin_bit_cast(float, u & 0xffff0000u);
}
__device__ __forceinline__ float sigmoidf_(float z) {
    return 1.0f / (1.0f + __expf(-z));
}
__device__ __forceinline__ bf16x8 ld_bf8(const unsigned short* p) {
    return __builtin_bit_cast(bf16x8, *(const us8*)p);
}
__device__ __forceinline__ bf16x8 pack8(float4 a, float4 b) {
    us8 u;
    u[0] = f2bf(a.x); u[1] = f2bf(a.y); u[2] = f2bf(a.z); u[3] = f2bf(a.w);
    u[4] = f2bf(b.x); u[5] = f2bf(b.y); u[6] = f2bf(b.z); u[7] = f2bf(b.w);
    return __builtin_bit_cast(bf16x8, u);
}

// ---------------------------------------------------------------------------
// K1: phaseA (blocks [0,2304)) || perm3+red3 (blocks [2304,11520)), 256 thr.
// ---------------------------------------------------------------------------
__global__ __launch_bounds__(256) void pre_kernel(
    const float* __restrict__ x2, const float* __restrict__ x3,
    const float* __restrict__ W1, const float* __restrict__ b1,
    float* __restrict__ wsA, unsigned short* __restrict__ wsB,
    unsigned short* __restrict__ wsC,
    unsigned short* __restrict__ X0, unsigned short* __restrict__ XA,
    unsigned short* __restrict__ XB, unsigned short* __restrict__ red3)
{
    __shared__ float xr[4][32];
    __shared__ float rowf[768];
    __shared__ float pex[12][16];
    __shared__ float pfa[12][16];
    const int t = threadIdx.x;

    if (blockIdx.x < 2304) {
        // ----------------- phaseA (verbatim, rounds 4-9) -----------------
        if (t < 128) {
            const int pr2 = t >> 5, c = t & 31;
            const int gg = blockIdx.x * 4 + pr2;
            const int bb = gg / 2304, pp2 = gg % 2304, P = pp2 / 48, Q = pp2 % 48;
            const float* base = x2 + (size_t)bb * 36864;
            xr[pr2][c] = (c < 16) ? base[(P * 48 + Q) * 16 + c]
                                  : base[(Q * 48 + P) * 16 + (c - 16)];
        }
        __syncthreads();
        const int pr = t >> 6, h = t & 63;
        const int g = blockIdx.x * 4 + pr;
        float a = b1[h], bacc = 0.f, cacc = 0.f;
#pragma unroll
        for (int c = 0; c < 16; ++c) {
            const float xpq = xr[pr][c], xqp = xr[pr][16 + c];
            a    += xpq * W1[(  0 + c) * 64 + h] + xqp * W1[( 64 + c) * 64 + h];
            bacc += xpq * W1[( 32 + c) * 64 + h] + xqp * W1[( 96 + c) * 64 + h];
            cacc += xpq * W1[(128 + c) * 64 + h] + xqp * W1[(160 + c) * 64 + h];
        }
        const size_t o = (size_t)g * 64 + h;
        wsA[o] = a;
        wsB[o] = f2bf(bacc);
        wsC[o] = f2bf(cacc);
    } else {
        // ----------------- perm3 (+parallel red3) -----------------
        const int g = blockIdx.x - 2304;          // (b*48+m1)*48+m2
        const int m2 = g % 48, t1 = g / 48, m1 = t1 % 48, b = t1 / 48;
        if (t < 192) {
            const int m3 = t >> 2, cq = (t & 3) * 4;
            const float4 v = *(const float4*)(x3 + (size_t)g * 768 + m3 * 16 + cq);
            *(float4*)(rowf + m3 * 16 + cq) = v;
            const uint2 u = make_uint2(pk2(v.x, v.y), pk2(v.z, v.w));
            *(uint2*)(X0 + (size_t)g * 768 + m3 * 16 + cq) = u;
            *(uint2*)(XA + (((size_t)(b * 48 + m1) * 48 + m3) * 48 + m2) * 16 + cq) = u;
            *(uint2*)(XB + (((size_t)(b * 48 + m2) * 48 + m3) * 48 + m1) * 16 + cq) = u;
        }
        __syncthreads();
        const bool mij = (m1 != m2);
        if (t < 192) {
            const int kk = t >> 4, c = t & 15;    // 12 k-chunks x 16 ch
            float ex = -__builtin_inff(), fa = __builtin_inff();
#pragma unroll
            for (int k4 = 0; k4 < 4; ++k4) {
                const int k = kk * 4 + k4;
                const bool m = mij & (k != m1) & (k != m2);
                const float vv = rowf[k * 16 + c];
                ex = fmaxf(ex, m ? vv : 0.f);
                fa = fminf(fa, m ? vv : 1.f);
            }
            pex[kk][c] = ex;
            pfa[kk][c] = fa;
        }
        __syncthreads();
        if (t < 16) {
            const int c = t;
            float ex = -__builtin_inff(), fa = __builtin_inff();
#pragma unroll
            for (int kk = 0; kk < 12; ++kk) {
                ex = fmaxf(ex, pex[kk][c]);
                fa = fminf(fa, pfa[kk][c]);
            }
            *(unsigned int*)(red3 + (size_t)g * 32 + 2 * c) = pk2(ex, fa);
        }
    }
}

// ---------------------------------------------------------------------------
// K2: y3 (blocks [0,1152)) || y2 ([1152,1344)) || y01 ([1344,1349)), 192 thr.
// ---------------------------------------------------------------------------
__global__ __launch_bounds__(192, 3) void main_kernel(
    const unsigned short* __restrict__ X0,
    const unsigned short* __restrict__ XA,
    const unsigned short* __restrict__ XB,
    const float* __restrict__ W1_3, const float* __restrict__ W2_3,
    const float* __restrict__ b2_3,
    const float* __restrict__ wsA,
    const unsigned short* __restrict__ wsB,
    const unsigned short* __restrict__ wsC,
    const float* __restrict__ x1, const float* __restrict__ x2,
    const float* __restrict__ W1_2, const float* __restrict__ b1_2,
    const float* __restrict__ W2_2, const float* __restrict__ b2_2,
    const unsigned short* __restrict__ red3,
    const float* __restrict__ x0,
    const float* __restrict__ W1_0, const float* __restrict__ b1_0,
    const float* __restrict__ W2_0, const float* __restrict__ b2_0,
    const float* __restrict__ W1_1, const float* __restrict__ b1_1,
    const float* __restrict__ W2_1, const float* __restrict__ b2_1,
    float* __restrict__ out)
{
    __shared__ __align__(16) unsigned short w1t[64 * 136];   // y3:104 y2:136 y01:72
    __shared__ __align__(16) unsigned short red2l[48 * 32];
    __shared__ float t0l[4][56];
    __shared__ float hl[4][72];
    const int t = threadIdx.x;
    const int w = t >> 6, lane = t & 63, lr = lane & 15, lg = lane >> 4;

    if (blockIdx.x < 1152) {
        // ----------------- y3 (round-9 body + Av prefetch) -----------------
        float* y3out = out + 150592;
#pragma unroll
        for (int p = 0; p < 16; ++p) {
            const int e = p * 192 + t;
            const int h = e & 63, kk = (e >> 6) * 2;
            const int r0 = 16 + ((kk >> 4) << 5) + (kk & 15);
            *(unsigned int*)(w1t + h * 104 + kk) =
                pk2(W1_3[r0 * 64 + h], W1_3[(r0 + 1) * 64 + h]);
        }
        __syncthreads();

        bf16x8 w1f[4][3];
#pragma unroll
        for (int n = 0; n < 4; ++n)
#pragma unroll
            for (int ks = 0; ks < 3; ++ks)
                w1f[n][ks] = ld_bf8(w1t + (16 * n + lr) * 104 + 32 * ks + 8 * lg);

        bf16x8 w2f[2];
#pragma unroll
        for (int m = 0; m < 2; ++m) {
            us8 u;
#pragma unroll
            for (int e = 0; e < 8; ++e) {
                const int ch = 16 * (e >> 1) + 4 * lg + 2 * (e & 1) + m;
                u[e] = f2bf(W2_3[ch * 16 + lr]);
            }
            w2f[m] = __builtin_bit_cast(bf16x8, u);
        }
        const float4 b2v = *(const float4*)(b2_3 + 4 * lg);
        const int row = 16 * w + lr;
        const int roff = row * 16 + 8 * (lg & 1);
        const bool hi = (lg >> 1) != 0;

        const int g0 = blockIdx.x * Y3_TILES;
        const int b = g0 / 2304, pp = g0 % 2304, i = pp / 48, j0 = pp % 48;

        const size_t baseB = ((size_t)((b * 48 + i) * 48 + row)) * 64 + 4 * lg;
        uint2 Bu[4];
#pragma unroll
        for (int n = 0; n < 4; ++n) Bu[n] = *(const uint2*)(wsB + baseB + 16 * n);

        const size_t rowIJ = ((size_t)(b * 48 + i) * 48) * 768;

        // prologue: tile 0 xf + C + A loads
        bf16x8 xc0, xc1, xc2;
        uint2 Cu[4];
        float4 Av[4];
        {
            const size_t bIJ = rowIJ + (size_t)j0 * 768;
            const size_t bJI = ((size_t)(b * 48 + j0) * 48 + i) * 768;
            xc0 = ld_bf8((hi ? XA + bIJ : X0 + bIJ) + roff);
            xc1 = ld_bf8((hi ? XB + bIJ : X0 + bJI) + roff);
            xc2 = ld_bf8((hi ? XB + bJI : XA + bJI) + roff);
            const size_t baseC = ((size_t)((b * 48 + j0) * 48 + row)) * 64 + 4 * lg;
            const size_t baseA = ((size_t)((b * 48 + i) * 48 + j0)) * 64 + 4 * lg;
#pragma unroll
            for (int n = 0; n < 4; ++n) {
                Cu[n] = *(const uint2*)(wsC + baseC + 16 * n);
                Av[n] = *(const float4*)(wsA + baseA + 16 * n);
            }
        }

#pragma unroll
        for (int it = 0; it < Y3_TILES; ++it) {
            const int j = j0 + it;
            bf16x8 xn0, xn1, xn2;
            uint2 Cn[4];
            float4 An[4];
            if (it < Y3_TILES - 1) {
                const int jn = j + 1;
                const size_t bIJ = rowIJ + (size_t)jn * 768;
                const size_t bJI = ((size_t)(b * 48 + jn) * 48 + i) * 768;
                xn0 = ld_bf8((hi ? XA + bIJ : X0 + bIJ) + roff);
                xn1 = ld_bf8((hi ? XB + bIJ : X0 + bJI) + roff);
                xn2 = ld_bf8((hi ? XB + bJI : XA + bJI) + roff);
                const size_t baseC = ((size_t)((b * 48 + jn) * 48 + row)) * 64 + 4 * lg;
                const size_t baseA = ((size_t)((b * 48 + i) * 48 + jn)) * 64 + 4 * lg;
#pragma unroll
                for (int n = 0; n < 4; ++n) {
                    Cn[n] = *(const uint2*)(wsC + baseC + 16 * n);
                    An[n] = *(const float4*)(wsA + baseA + 16 * n);
                }
            }
            f32x4 acc[4];
#pragma unroll
            for (int n = 0; n < 4; ++n) {
                acc[n] = f32x4{0.f, 0.f, 0.f, 0.f};
                acc[n] = __builtin_amdgcn_mfma_f32_16x16x32_bf16(w1f[n][0], xc0, acc[n], 0, 0, 0);
                acc[n] = __builtin_amdgcn_mfma_f32_16x16x32_bf16(w1f[n][1], xc1, acc[n], 0, 0, 0);
                acc[n] = __builtin_amdgcn_mfma_f32_16x16x32_bf16(w1f[n][2], xc2, acc[n], 0, 0, 0);
            }
#pragma unroll
            for (int n = 0; n < 4; ++n) {
                acc[n][0] = fmaxf(acc[n][0] + Av[n].x + bflo(Bu[n].x) + bflo(Cu[n].x), 0.f);
                acc[n][1] = fmaxf(acc[n][1] + Av[n].y + bfhi(Bu[n].x) + bfhi(Cu[n].x), 0.f);
                acc[n][2] = fmaxf(acc[n][2] + Av[n].z + bflo(Bu[n].y) + bflo(Cu[n].y), 0.f);
                acc[n][3] = fmaxf(acc[n][3] + Av[n].w + bfhi(Bu[n].y) + bfhi(Cu[n].y), 0.f);
            }
            bf16x8 hf[2];
#pragma unroll
            for (int m = 0; m < 2; ++m) {
                us8 u;
#pragma unroll
                for (int e = 0; e < 8; ++e)
                    u[e] = f2bf(acc[e >> 1][2 * (e & 1) + m]);
                hf[m] = __builtin_bit_cast(bf16x8, u);
            }
            f32x4 o2 = {0.f, 0.f, 0.f, 0.f};
            o2 = __builtin_amdgcn_mfma_f32_16x16x32_bf16(w2f[0], hf[0], o2, 0, 0, 0);
            o2 = __builtin_amdgcn_mfma_f32_16x16x32_bf16(w2f[1], hf[1], o2, 0, 0, 0);
            float4 ov;
            ov.x = sigmoidf_(o2[0] + b2v.x);
            ov.y = sigmoidf_(o2[1] + b2v.y);
            ov.z = sigmoidf_(o2[2] + b2v.z);
            ov.w = sigmoidf_(o2[3] + b2v.w);
            *(float4*)(y3out + (size_t)(g0 + it) * 768 + row * 16 + 4 * lg) = ov;
            if (it < Y3_TILES - 1) {
                xc0 = xn0; xc1 = xn1; xc2 = xn2;
#pragma unroll
                for (int n = 0; n < 4; ++n) { Cu[n] = Cn[n]; Av[n] = An[n]; }
            }
        }
    } else if (blockIdx.x < 1344) {
        // ----------------- y2 (round-5..9 body, verbatim) -----------------
        float* y2out = out + 3136;
#pragma unroll
        for (int p = 0; p < 22; ++p) {
            const int e = p * 192 + t;
            if (e < 4096) {
                const int h = e & 63, k2 = e >> 6;
                *(unsigned int*)(w1t + h * 136 + 2 * k2) =
                    pk2(W1_2[(2 * k2) * 64 + h], W1_2[(2 * k2 + 1) * 64 + h]);
            }
        }
        __syncthreads();

        bf16x8 w1f[4][4];
#pragma unroll
        for (int n = 0; n < 4; ++n)
#pragma unroll
            for (int ks = 0; ks < 4; ++ks)
                w1f[n][ks] = ld_bf8(w1t + (16 * n + lr) * 136 + 32 * ks + 8 * lg);

        bf16x8 w2f[2];
#pragma unroll
        for (int m = 0; m < 2; ++m) {
            us8 u;
#pragma unroll
            for (int e = 0; e < 8; ++e) {
                const int ch = 16 * (e >> 1) + 4 * lg + 2 * (e & 1) + m;
                u[e] = f2bf(W2_2[ch * 16 + lr]);
            }
            w2f[m] = __builtin_bit_cast(bf16x8, u);
        }
        float4 b1v[4];
#pragma unroll
        for (int n = 0; n < 4; ++n) b1v[n] = *(const float4*)(b1_2 + 16 * n + 4 * lg);
        const float4 b2v = *(const float4*)(b2_2 + 4 * lg);

        const int bq = blockIdx.x - 1152;          // b*48 + i
        const int b = bq / 48, i = bq % 48;
        const float* x2b = x2 + (size_t)b * 36864;
        const int row = 16 * w + lr;               // = j
        const int j = row;
        const int c0 = 8 * (lg & 1);
        const bool hi = (lg >> 1) != 0;

        const float* a0 = hi ? (x2b + (i * 48 + j) * 16 + c0) : (x1 + (b * 48 + i) * 16 + c0);
        const float* a2 = hi ? (x2b + (j * 48 + i) * 16 + c0) : (x1 + (b * 48 + j) * 16 + c0);
        const unsigned short* r1 = red3 + ((size_t)(b * 48 + i) * 48 + j) * 32 + (hi ? 16 : 0) + c0;
        const unsigned short* r3 = red3 + ((size_t)(b * 48 + j) * 48 + i) * 32 + (hi ? 16 : 0) + c0;

        const bf16x8 xf0 = pack8(*(const float4*)a0, *(const float4*)(a0 + 4));
        const bf16x8 xf1 = ld_bf8(r1);
        const bf16x8 xf2 = pack8(*(const float4*)a2, *(const float4*)(a2 + 4));
        const bf16x8 xf3 = ld_bf8(r3);

        f32x4 acc[4];
#pragma unroll
        for (int n = 0; n < 4; ++n) {
            acc[n] = f32x4{0.f, 0.f, 0.f, 0.f};
            acc[n] = __builtin_amdgcn_mfma_f32_16x16x32_bf16(w1f[n][0], xf0, acc[n], 0, 0, 0);
            acc[n] = __builtin_amdgcn_mfma_f32_16x16x32_bf16(w1f[n][1], xf1, acc[n], 0, 0, 0);
            acc[n] = __builtin_amdgcn_mfma_f32_16x16x32_bf16(w1f[n][2], xf2, acc[n], 0, 0, 0);
            acc[n] = __builtin_amdgcn_mfma_f32_16x16x32_bf16(w1f[n][3], xf3, acc[n], 0, 0, 0);
        }
#pragma unroll
        for (int n = 0; n < 4; ++n) {
            acc[n][0] = fmaxf(acc[n][0] + b1v[n].x, 0.f);
            acc[n][1] = fmaxf(acc[n][1] + b1v[n].y, 0.f);
            acc[n][2] = fmaxf(acc[n][2] + b1v[n].z, 0.f);
            acc[n][3] = fmaxf(acc[n][3] + b1v[n].w, 0.f);
        }
        bf16x8 hf[2];
#pragma unroll
        for (int m = 0; m < 2; ++m) {
            us8 u;
#pragma unroll
            for (int e = 0; e < 8; ++e)
                u[e] = f2bf(acc[e >> 1][2 * (e & 1) + m]);
            hf[m] = __builtin_bit_cast(bf16x8, u);
        }
        f32x4 o2 = {0.f, 0.f, 0.f, 0.f};
        o2 = __builtin_amdgcn_mfma_f32_16x16x32_bf16(w2f[0], hf[0], o2, 0, 0, 0);
        o2 = __builtin_amdgcn_mfma_f32_16x16x32_bf16(w2f[1], hf[1], o2, 0, 0, 0);
        float4 ov;
        ov.x = sigmoidf_(o2[0] + b2v.x);
        ov.y = sigmoidf_(o2[1] + b2v.y);
        ov.z = sigmoidf_(o2[2] + b2v.z);
        ov.w = sigmoidf_(o2[3] + b2v.w);
        *(float4*)(y2out + ((size_t)bq * 48 + row) * 16 + 4 * lg) = ov;
    } else if (blockIdx.x < 1348) {
        // ----------------- y1 (round-6 body, verbatim) -----------------
        const int b = blockIdx.x - 1344;
#pragma unroll
        for (int p = 0; p < 11; ++p) {
            const int e = p * 192 + t;
            if (e < 2048) {
                const int h = e & 63, k2 = e >> 6;
                *(unsigned int*)(w1t + h * 72 + 2 * k2) =
                    pk2(W1_1[(2 * k2) * 64 + h], W1_1[(2 * k2 + 1) * 64 + h]);
            }
        }
        const float* x2b = x2 + (size_t)b * 36864;
#pragma unroll
        for (int s4 = 0; s4 < 4; ++s4) {
            const int s = t + 192 * s4;            // 0..767
            const int i = s >> 4, c = s & 15;
            const float* p = x2b + i * 768 + c;
            float ex = -__builtin_inff(), fa = __builtin_inff();
#pragma unroll 8
            for (int jj = 0; jj < 48; ++jj) {
                const bool m = (jj != i);
                const float v = p[jj * 16];
                ex = fmaxf(ex, m ? v : 0.f);
                fa = fminf(fa, m ? v : 1.f);
            }
            *(unsigned int*)(red2l + i * 32 + 2 * c) = pk2(ex, fa);
        }
        __syncthreads();

        const int i = 16 * w + lr;
        const int rho = b * 48 + i;
        bf16x8 w1f[4][2];
#pragma unroll
        for (int n = 0; n < 4; ++n)
#pragma unroll
            for (int ks = 0; ks < 2; ++ks)
                w1f[n][ks] = ld_bf8(w1t + (16 * n + lr) * 72 + 32 * ks + 8 * lg);
        bf16x8 w2f[2];
#pragma unroll
        for (int m = 0; m < 2; ++m) {
            us8 u;
#pragma unroll
            for (int e = 0; e < 8; ++e) {
                const int ch = 16 * (e >> 1) + 4 * lg + 2 * (e & 1) + m;
                u[e] = f2bf(W2_1[ch * 16 + lr]);
            }
            w2f[m] = __builtin_bit_cast(bf16x8, u);
        }
        float4 b1v[4];
#pragma unroll
        for (int n = 0; n < 4; ++n) b1v[n] = *(const float4*)(b1_1 + 16 * n + 4 * lg);
        const float4 b2v = *(const float4*)(b2_1 + 4 * lg);

        const int c0 = 8 * (lg & 1);
        const float* a0 = (lg < 2) ? (x0 + b * 16 + c0) : (x1 + rho * 16 + c0);
        const bf16x8 xf0 = pack8(*(const float4*)a0, *(const float4*)(a0 + 4));
        const bf16x8 xf1 = ld_bf8(red2l + i * 32 + 8 * lg);

        f32x4 acc[4];
#pragma unroll
        for (int n = 0; n < 4; ++n) {
            acc[n] = f32x4{0.f, 0.f, 0.f, 0.f};
            acc[n] = __builtin_amdgcn_mfma_f32_16x16x32_bf16(w1f[n][0], xf0, acc[n], 0, 0, 0);
            acc[n] = __builtin_amdgcn_mfma_f32_16x16x32_bf16(w1f[n][1], xf1, acc[n], 0, 0, 0);
        }
#pragma unroll
        for (int n = 0; n < 4; ++n) {
            acc[n][0] = fmaxf(acc[n][0] + b1v[n].x, 0.f);
            acc[n][1] = fmaxf(acc[n][1] + b1v[n].y, 0.f);
            acc[n][2] = fmaxf(acc[n][2] + b1v[n].z, 0.f);
            acc[n][3] = fmaxf(acc[n][3] + b1v[n].w, 0.f);
        }
        bf16x8 hf[2];
#pragma unroll
        for (int m = 0; m < 2; ++m) {
            us8 u;
#pragma unroll
            for (int e = 0; e < 8; ++e)
                u[e] = f2bf(acc[e >> 1][2 * (e & 1) + m]);
            hf[m] = __builtin_bit_cast(bf16x8, u);
        }
        f32x4 o2 = {0.f, 0.f, 0.f, 0.f};
        o2 = __builtin_amdgcn_mfma_f32_16x16x32_bf16(w2f[0], hf[0], o2, 0, 0, 0);
        o2 = __builtin_amdgcn_mfma_f32_16x16x32_bf16(w2f[1], hf[1], o2, 0, 0, 0);
        float4 ov;
        ov.x = sigmoidf_(o2[0] + b2v.x);
        ov.y = sigmoidf_(o2[1] + b2v.y);
        ov.z = sigmoidf_(o2[2] + b2v.z);
        ov.w = sigmoidf_(o2[3] + b2v.w);
        *(float4*)(out + 64 + (size_t)rho * 16 + 4 * lg) = ov;
    } else {
        // ----------------- y0 (round-6 body, verbatim) -----------------
        if (t < 64) {
            const int b = t >> 4, c = t & 15;
            const float* p = x1 + b * 768 + c;
            float ex = -__builtin_inff(), fa = __builtin_inff();
#pragma unroll 8
            for (int n = 0; n < 48; ++n) {
                const float v = p[n * 16];
                ex = fmaxf(ex, v);
                fa = fminf(fa, v);
            }
            t0l[b][c] = x0[b * 16 + c];
            t0l[b][16 + 2 * c] = ex;
            t0l[b][17 + 2 * c] = fa;
        }
        __syncthreads();
        if (t < 64) {
            const int h = t;
            float ac0 = b1_0[h], ac1 = ac0, ac2 = ac0, ac3 = ac0;
#pragma unroll
            for (int c = 0; c < 48; ++c) {
                const float wv = W1_0[c * 64 + h];
                ac0 = fmaf(t0l[0][c], wv, ac0);
                ac1 = fmaf(t0l[1][c], wv, ac1);
                ac2 = fmaf(t0l[2][c], wv, ac2);
                ac3 = fmaf(t0l[3][c], wv, ac3);
            }
            hl[0][h] = fmaxf(ac0, 0.f);
            hl[1][h] = fmaxf(ac1, 0.f);
            hl[2][h] = fmaxf(ac2, 0.f);
            hl[3][h] = fmaxf(ac3, 0.f);
        }
        __syncthreads();
        if (t < 64) {
            const int b = t >> 4, o = t & 15;
            float a = b2_0[o];
#pragma unroll
            for (int h = 0; h < 64; ++h)
                a = fmaf(hl[b][h], W2_0[h * 16 + o], a);
            out[b * 16 + o] = sigmoidf_(a);
        }
    }
}

// ---------------------------------------------------------------------------
// Standalone kernels for fallback tiers (all previously verified).
// ---------------------------------------------------------------------------
__global__ __launch_bounds__(256) void phaseA_kernel(
    const float* __restrict__ x2, const float* __restrict__ W1,
    const float* __restrict__ b1,
    float* __restrict__ wsA, unsigned short* __restrict__ wsB,
    unsigned short* __restrict__ wsC)
{
    __shared__ float xr[4][32];
    const int t = threadIdx.x;
    if (t < 128) {
        const int pr2 = t >> 5, c = t & 31;
        const int gg = blockIdx.x * 4 + pr2;
        const int bb = gg / 2304, pp2 = gg % 2304, P = pp2 / 48, Q = pp2 % 48;
        const float* base = x2 + (size_t)bb * 36864;
        xr[pr2][c] = (c < 16) ? base[(P * 48 + Q) * 16 + c]
                              : base[(Q * 48 + P) * 16 + (c - 16)];
    }
    __syncthreads();
    const int pr = t >> 6, h = t & 63;
    const int g = blockIdx.x * 4 + pr;
    float a = b1[h], bacc = 0.f, cacc = 0.f;
#pragma unroll
    for (int c = 0; c < 16; ++c) {
        const float xpq = xr[pr][c], xqp = xr[pr][16 + c];
        a    += xpq * W1[(  0 + c) * 64 + h] + xqp * W1[( 64 + c) * 64 + h];
        bacc += xpq * W1[( 32 + c) * 64 + h] + xqp * W1[( 96 + c) * 64 + h];
        cacc += xpq * W1[(128 + c) * 64 + h] + xqp * W1[(160 + c) * 64 + h];
    }
    const size_t o = (size_t)g * 64 + h;
    wsA[o] = a;
    wsB[o] = f2bf(bacc);
    wsC[o] = f2bf(cacc);
}

__global__ __launch_bounds__(192, 3) void y3_gather_kernel(
    const float* __restrict__ x3,
    const float* __restrict__ W1, const float* __restrict__ W2,
    const float* __restrict__ b2,
    const float* __restrict__ wsA,
    const unsigned short* __restrict__ wsB,
    const unsigned short* __restrict__ wsC,
    float* __restrict__ out)
{
    __shared__ __align__(16) unsigned short w1t[64 * 104];
    const int t = threadIdx.x;
    const int w = t >> 6, lane = t & 63, lr = lane & 15, lg = lane >> 4;
#pragma unroll
    for (int p = 0; p < 16; ++p) {
        const int e = p * 192 + t;
        const int h = e & 63, kk = (e >> 6) * 2;
        const int r0 = 16 + ((kk >> 4) << 5) + (kk & 15);
        *(unsigned int*)(w1t + h * 104 + kk) =
            pk2(W1[r0 * 64 + h], W1[(r0 + 1) * 64 + h]);
    }
    __syncthreads();
    bf16x8 w1f[4][3];
#pragma unroll
    for (int n = 0; n < 4; ++n)
#pragma unroll
        for (int ks = 0; ks < 3; ++ks)
            w1f[n][ks] = ld_bf8(w1t + (16 * n + lr) * 104 + 32 * ks + 8 * lg);
    bf16x8 w2f[2];
#pragma unroll
    for (int m = 0; m < 2; ++m) {
        us8 u;
#pragma unroll
        for (int e = 0; e < 8; ++e) {
            const int ch = 16 * (e >> 1) + 4 * lg + 2 * (e & 1) + m;
            u[e] = f2bf(W2[ch * 16 + lr]);
        }
        w2f[m] = __builtin_bit_cast(bf16x8, u);
    }
    const float4 b2v = *(const float4*)(b2 + 4 * lg);
    const int row = 16 * w + lr;
    const int c0 = 8 * (lg & 1);
    const bool hi = (lg >> 1) != 0;
    for (int it = 0; it < 4; ++it) {
        const int g = blockIdx.x * 4 + it;
        const int b = g / 2304, pp = g % 2304, i = pp / 48, j = pp % 48;
        const float* xb3 = x3 + (size_t)b * 1769472;
        const int sb0 = i * 36864 + j * 768 + row * 16;
        const int sb1 = i * 36864 + row * 768 + j * 16;
        const int sb2 = j * 36864 + i * 768 + row * 16;
        const int sb3 = row * 36864 + i * 768 + j * 16;
        const int sb4 = j * 36864 + row * 768 + i * 16;
        const int sb5 = row * 36864 + j * 768 + i * 16;
        const float* p0 = xb3 + (hi ? sb1 : sb0) + c0;
        const float* p1 = xb3 + (hi ? sb3 : sb2) + c0;
        const float* p2 = xb3 + (hi ? sb5 : sb4) + c0;
        const bf16x8 xf0 = pack8(*(const float4*)p0, *(const float4*)(p0 + 4));
        const bf16x8 xf1 = pack8(*(const float4*)p1, *(const float4*)(p1 + 4));
        const bf16x8 xf2 = pack8(*(const float4*)p2, *(const float4*)(p2 + 4));
        f32x4 acc[4];
#pragma unroll
        for (int n = 0; n < 4; ++n) {
            acc[n] = f32x4{0.f, 0.f, 0.f, 0.f};
            acc[n] = __builtin_amdgcn_mfma_f32_16x16x32_bf16(w1f[n][0], xf0, acc[n], 0, 0, 0);
            acc[n] = __builtin_amdgcn_mfma_f32_16x16x32_bf16(w1f[n][1], xf1, acc[n], 0, 0, 0);
            acc[n] = __builtin_amdgcn_mfma_f32_16x16x32_bf16(w1f[n][2], xf2, acc[n], 0, 0, 0);
        }
        const size_t baseB = ((size_t)((b * 48 + i) * 48 + row)) * 64 + 4 * lg;
        const size_t baseC = ((size_t)((b * 48 + j) * 48 + row)) * 64 + 4 * lg;
        const size_t baseA = ((size_t)((b * 48 + i) * 48 + j)) * 64 + 4 * lg;
#pragma unroll
        for (int n = 0; n < 4; ++n) {
            const uint2 Bu = *(const uint2*)(wsB + baseB + 16 * n);
            const uint2 Cu = *(const uint2*)(wsC + baseC + 16 * n);
            const float4 Au = *(const float4*)(wsA + baseA + 16 * n);
            acc[n][0] = fmaxf(acc[n][0] + Au.x + bflo(Bu.x) + bflo(Cu.x), 0.f);
            acc[n][1] = fmaxf(acc[n][1] + Au.y + bfhi(Bu.x) + bfhi(Cu.x), 0.f);
            acc[n][2] = fmaxf(acc[n][2] + Au.z + bflo(Bu.y) + bflo(Cu.y), 0.f);
            acc[n][3] = fmaxf(acc[n][3] + Au.w + bfhi(Bu.y) + bfhi(Cu.y), 0.f);
        }
        bf16x8 hf[2];
#pragma unroll
        for (int m = 0; m < 2; ++m) {
            us8 u;
#pragma unroll
            for (int e = 0; e < 8; ++e)
                u[e] = f2bf(acc[e >> 1][2 * (e & 1) + m]);
            hf[m] = __builtin_bit_cast(bf16x8, u);
        }
        f32x4 o2 = {0.f, 0.f, 0.f, 0.f};
        o2 = __builtin_amdgcn_mfma_f32_16x16x32_bf16(w2f[0], hf[0], o2, 0, 0, 0);
        o2 = __builtin_amdgcn_mfma_f32_16x16x32_bf16(w2f[1], hf[1], o2, 0, 0, 0);
        float4 ov;
        ov.x = sigmoidf_(o2[0] + b2v.x);
        ov.y = sigmoidf_(o2[1] + b2v.y);
        ov.z = sigmoidf_(o2[2] + b2v.z);
        ov.w = sigmoidf_(o2[3] + b2v.w);
        *(float4*)(out + (size_t)g * 768 + row * 16 + 4 * lg) = ov;
    }
}

__global__ __launch_bounds__(256) void red3_kernel(
    const float* __restrict__ x3, unsigned short* __restrict__ red3)
{
    const int slot = blockIdx.x * 256 + threadIdx.x;
    const int c = slot & 15;
    const int q = slot >> 4;
    const int j = q % 48, pi = q / 48, i = pi % 48;
    const float* p = x3 + (size_t)q * 768 + c;
    float ex = -__builtin_inff(), fa = __builtin_inff();
    const bool mij = (i != j);
#pragma unroll 8
    for (int k = 0; k < 48; ++k) {
        const bool m = mij & (k != i) & (k != j);
        const float v = p[k * 16];
        ex = fmaxf(ex, m ? v : 0.f);
        fa = fminf(fa, m ? v : 1.f);
    }
    *(unsigned int*)(red3 + (size_t)q * 32 + 2 * c) = pk2(ex, fa);
}

__global__ __launch_bounds__(192, 3) void y2_mlp_kernel(
    const float* __restrict__ x1, const float* __restrict__ x2,
    const float* __restrict__ W1, const float* __restrict__ b1,
    const float* __restrict__ W2, const float* __restrict__ b2,
    const unsigned short* __restrict__ red3, float* __restrict__ out)
{
    __shared__ __align__(16) unsigned short w1t[64 * 136];
    const int t = threadIdx.x;
    const int w = t >> 6, lane = t & 63, lr = lane & 15, lg = lane >> 4;
#pragma unroll
    for (int p = 0; p < 22; ++p) {
        const int e = p * 192 + t;
        if (e < 4096) {
            const int h = e & 63, k2 = e >> 6;
            *(unsigned int*)(w1t + h * 136 + 2 * k2) =
                pk2(W1[(2 * k2) * 64 + h], W1[(2 * k2 + 1) * 64 + h]);
        }
    }
    __syncthreads();
    bf16x8 w1f[4][4];
#pragma unroll
    for (int n = 0; n < 4; ++n)
#pragma unroll
        for (int ks = 0; ks < 4; ++ks)
            w1f[n][ks] = ld_bf8(w1t + (16 * n + lr) * 136 + 32 * ks + 8 * lg);
    bf16x8 w2f[2];
#pragma unroll
    for (int m = 0; m < 2; ++m) {
        us8 u;
#pragma unroll
        for (int e = 0; e < 8; ++e) {
            const int ch = 16 * (e >> 1) + 4 * lg + 2 * (e & 1) + m;
            u[e] = f2bf(W2[ch * 16 + lr]);
        }
        w2f[m] = __builtin_bit_cast(bf16x8, u);
    }
    float4 b1v[4];
#pragma unroll
    for (int n = 0; n < 4; ++n) b1v[n] = *(const float4*)(b1 + 16 * n + 4 * lg);
    const float4 b2v = *(const float4*)(b2 + 4 * lg);
    const int bq = blockIdx.x;
    const int b = bq / 48, i = bq % 48;
    const float* x2b = x2 + (size_t)b * 36864;
    const int row = 16 * w + lr;
    const int j = row;
    const int c0 = 8 * (lg & 1);
    const bool hi = (lg >> 1) != 0;
    const float* a0 = hi ? (x2b + (i * 48 + j) * 16 + c0) : (x1 + (b * 48 + i) * 16 + c0);
    const float* a2 = hi ? (x2b + (j * 48 + i) * 16 + c0) : (x1 + (b * 48 + j) * 16 + c0);
    const unsigned short* r1 = red3 + ((size_t)(b * 48 + i) * 48 + j) * 32 + (hi ? 16 : 0) + c0;
    const unsigned short* r3 = red3 + ((size_t)(b * 48 + j) * 48 + i) * 32 + (hi ? 16 : 0) + c0;
    const bf16x8 xf0 = pack8(*(const float4*)a0, *(const float4*)(a0 + 4));
    const bf16x8 xf1 = ld_bf8(r1);
    const bf16x8 xf2 = pack8(*(const float4*)a2, *(const float4*)(a2 + 4));
    const bf16x8 xf3 = ld_bf8(r3);
    f32x4 acc[4];
#pragma unroll
    for (int n = 0; n < 4; ++n) {
        acc[n] = f32x4{0.f, 0.f, 0.f, 0.f};
        acc[n] = __builtin_amdgcn_mfma_f32_16x16x32_bf16(w1f[n][0], xf0, acc[n], 0, 0, 0);
        acc[n] = __builtin_amdgcn_mfma_f32_16x16x32_bf16(w1f[n][1], xf1, acc[n], 0, 0, 0);
        acc[n] = __builtin_amdgcn_mfma_f32_16x16x32_bf16(w1f[n][2], xf2, acc[n], 0, 0, 0);
        acc[n] = __builtin_amdgcn_mfma_f32_16x16x32_bf16(w1f[n][3], xf3, acc[n], 0, 0, 0);
    }
#pragma unroll
    for (int n = 0; n < 4; ++n) {
        acc[n][0] = fmaxf(acc[n][0] + b1v[n].x, 0.f);
        acc[n][1] = fmaxf(acc[n][1] + b1v[n].y, 0.f);
        acc[n][2] = fmaxf(acc[n][2] + b1v[n].z, 0.f);
        acc[n][3] = fmaxf(acc[n][3] + b1v[n].w, 0.f);
    }
    bf16x8 hf[2];
#pragma unroll
    for (int m = 0; m < 2; ++m) {
        us8 u;
#pragma unroll
        for (int e = 0; e < 8; ++e)
            u[e] = f2bf(acc[e >> 1][2 * (e & 1) + m]);
        hf[m] = __builtin_bit_cast(bf16x8, u);
    }
    f32x4 o2 = {0.f, 0.f, 0.f, 0.f};
    o2 = __builtin_amdgcn_mfma_f32_16x16x32_bf16(w2f[0], hf[0], o2, 0, 0, 0);
    o2 = __builtin_amdgcn_mfma_f32_16x16x32_bf16(w2f[1], hf[1], o2, 0, 0, 0);
    float4 ov;
    ov.x = sigmoidf_(o2[0] + b2v.x);
    ov.y = sigmoidf_(o2[1] + b2v.y);
    ov.z = sigmoidf_(o2[2] + b2v.z);
    ov.w = sigmoidf_(o2[3] + b2v.w);
    *(float4*)(out + ((size_t)bq * 48 + row) * 16 + 4 * lg) = ov;
}

__global__ __launch_bounds__(192, 1) void y01_kernel(
    const float* __restrict__ x0, const float* __restrict__ x1,
    const float* __restrict__ x2,
    const float* __restrict__ W1_0, const float* __restrict__ b1_0,
    const float* __restrict__ W2_0, const float* __restrict__ b2_0,
    const float* __restrict__ W1_1, const float* __restrict__ b1_1,
    const float* __restrict__ W2_1, const float* __restrict__ b2_1,
    float* __restrict__ out)
{
    const int t = threadIdx.x;
    if (blockIdx.x < 4) {
        __shared__ __align__(16) unsigned short w1t[64 * 72];
        __shared__ __align__(16) unsigned short red2l[48 * 32];
        const int b = blockIdx.x;
#pragma unroll
        for (int p = 0; p < 11; ++p) {
            const int e = p * 192 + t;
            if (e < 2048) {
                const int h = e & 63, k2 = e >> 6;
                *(unsigned int*)(w1t + h * 72 + 2 * k2) =
                    pk2(W1_1[(2 * k2) * 64 + h], W1_1[(2 * k2 + 1) * 64 + h]);
            }
        }
        const float* x2b = x2 + (size_t)b * 36864;
#pragma unroll
        for (int s4 = 0; s4 < 4; ++s4) {
            const int s = t + 192 * s4;
            const int i = s >> 4, c = s & 15;
            const float* p = x2b + i * 768 + c;
            float ex = -__builtin_inff(), fa = __builtin_inff();
#pragma unroll 8
            for (int jj = 0; jj < 48; ++jj) {
                const bool m = (jj != i);
                const float v = p[jj * 16];
                ex = fmaxf(ex, m ? v : 0.f);
                fa = fminf(fa, m ? v : 1.f);
            }
            *(unsigned int*)(red2l + i * 32 + 2 * c) = pk2(ex, fa);
        }
        __syncthreads();
        const int w = t >> 6, lane = t & 63, lr = lane & 15, lg = lane >> 4;
        const int i = 16 * w + lr;
        const int rho = b * 48 + i;
        bf16x8 w1f[4][2];
#pragma unroll
        for (int n = 0; n < 4; ++n)
#pragma unroll
            for (int ks = 0; ks < 2; ++ks)
                w1f[n][ks] = ld_bf8(w1t + (16 * n + lr) * 72 + 32 * ks + 8 * lg);
        bf16x8 w2f[2];
#pragma unroll
        for (int m = 0; m < 2; ++m) {
            us8 u;
#pragma unroll
            for (int e = 0; e < 8; ++e) {
                const int ch = 16 * (e >> 1) + 4 * lg + 2 * (e & 1) + m;
                u[e] = f2bf(W2_1[ch * 16 + lr]);
            }
            w2f[m] = __builtin_bit_cast(bf16x8, u);
        }
        float4 b1v[4];
#pragma unroll
        for (int n = 0; n < 4; ++n) b1v[n] = *(const float4*)(b1_1 + 16 * n + 4 * lg);
        const float4 b2v = *(const float4*)(b2_1 + 4 * lg);
        const int c0 = 8 * (lg & 1);
        const float* a0 = (lg < 2) ? (x0 + b * 16 + c0) : (x1 + rho * 16 + c0);
        const bf16x8 xf0 = pack8(*(const float4*)a0, *(const float4*)(a0 + 4));
        const bf16x8 xf1 = ld_bf8(red2l + i * 32 + 8 * lg);
        f32x4 acc[4];
#pragma unroll
        for (int n = 0; n < 4; ++n) {
            acc[n] = f32x4{0.f, 0.f, 0.f, 0.f};
            acc[n] = __builtin_amdgcn_mfma_f32_16x16x32_bf16(w1f[n][0], xf0, acc[n], 0, 0, 0);
            acc[n] = __builtin_amdgcn_mfma_f32_16x16x32_bf16(w1f[n][1], xf1, acc[n], 0, 0, 0);
        }
#pragma unroll
        for (int n = 0; n < 4; ++n) {
            acc[n][0] = fmaxf(acc[n][0] + b1v[n].x, 0.f);
            acc[n][1] = fmaxf(acc[n][1] + b1v[n].y, 0.f);
            acc[n][2] = fmaxf(acc[n][2] + b1v[n].z, 0.f);
            acc[n][3] = fmaxf(acc[n][3] + b1v[n].w, 0.f);
        }
        bf16x8 hf[2];
#pragma unroll
        for (int m = 0; m < 2; ++m) {
            us8 u;
#pragma unroll
            for (int e = 0; e < 8; ++e)
                u[e] = f2bf(acc[e >> 1][2 * (e & 1) + m]);
            hf[m] = __builtin_bit_cast(bf16x8, u);
        }
        f32x4 o2 = {0.f, 0.f, 0.f, 0.f};
        o2 = __builtin_amdgcn_mfma_f32_16x16x32_bf16(w2f[0], hf[0], o2, 0, 0, 0);
        o2 = __builtin_amdgcn_mfma_f32_16x16x32_bf16(w2f[1], hf[1], o2, 0, 0, 0);
        float4 ov;
        ov.x = sigmoidf_(o2[0] + b2v.x);
        ov.y = sigmoidf_(o2[1] + b2v.y);
        ov.z = sigmoidf_(o2[2] + b2v.z);
        ov.w = sigmoidf_(o2[3] + b2v.w);
        *(float4*)(out + 64 + (size_t)rho * 16 + 4 * lg) = ov;
    } else {
        __shared__ float t0l[4][56];
        __shared__ float hl[4][72];
        if (t < 64) {
            const int b = t >> 4, c = t & 15;
            const float* p = x1 + b * 768 + c;
            float ex = -__builtin_inff(), fa = __builtin_inff();
#pragma unroll 8
            for (int n = 0; n < 48; ++n) {
                const float v = p[n * 16];
                ex = fmaxf(ex, v);
                fa = fminf(fa, v);
            }
            t0l[b][c] = x0[b * 16 + c];
            t0l[b][16 + 2 * c] = ex;
            t0l[b][17 + 2 * c] = fa;
        }
        __syncthreads();
        if (t < 64) {
            const int h = t;
            float ac0 = b1_0[h], ac1 = ac0, ac2 = ac0, ac3 = ac0;
#pragma unroll
            for (int c = 0; c < 48; ++c) {
                const float wv = W1_0[c * 64 + h];
                ac0 = fmaf(t0l[0][c], wv, ac0);
                ac1 = fmaf(t0l[1][c], wv, ac1);
                ac2 = fmaf(t0l[2][c], wv, ac2);
                ac3 = fmaf(t0l[3][c], wv, ac3);
            }
            hl[0][h] = fmaxf(ac0, 0.f);
            hl[1][h] = fmaxf(ac1, 0.f);
            hl[2][h] = fmaxf(ac2, 0.f);
            hl[3][h] = fmaxf(ac3, 0.f);
        }
        __syncthreads();
        if (t < 64) {
            const int b = t >> 4, o = t & 15;
            float a = b2_0[o];
#pragma unroll
            for (int h = 0; h < 64; ++h)
                a = fmaf(hl[b][h], W2_0[h * 16 + o], a);
            out[b * 16 + o] = sigmoidf_(a);
        }
    }
}

template <int NK>
__device__ __forceinline__ void mlp_head(
    const unsigned short* lds_in, const unsigned short* lds_w1t,
    const unsigned short* lds_w2t, const float* lds_b1, const float* lds_b2,
    unsigned short* lds_h, float* outp)
{
    constexpr int S = NK * 32 + 8;
    const int t = threadIdx.x;
    const int w = t >> 6, lr = t & 15, lg = (t >> 4) & 3;
    f32x4 acc0 = {0.f, 0.f, 0.f, 0.f};
    f32x4 acc1 = acc0, acc2 = acc0, acc3 = acc0;
    const unsigned short* pa = lds_in + (16 * w + lr) * S + lg * 8;
    const unsigned short* pb = lds_w1t + lr * S + lg * 8;
#pragma unroll
    for (int ks = 0; ks < NK; ++ks) {
        bf16x8 a = ld_bf8(pa + ks * 32);
        acc0 = __builtin_amdgcn_mfma_f32_16x16x32_bf16(a, ld_bf8(pb + 0 * 16 * S + ks * 32), acc0, 0, 0, 0);
        acc1 = __builtin_amdgcn_mfma_f32_16x16x32_bf16(a, ld_bf8(pb + 1 * 16 * S + ks * 32), acc1, 0, 0, 0);
        acc2 = __builtin_amdgcn_mfma_f32_16x16x32_bf16(a, ld_bf8(pb + 2 * 16 * S + ks * 32), acc2, 0, 0, 0);
        acc3 = __builtin_amdgcn_mfma_f32_16x16x32_bf16(a, ld_bf8(pb + 3 * 16 * S + ks * 32), acc3, 0, 0, 0);
    }
    const int hrow = 16 * w + lg * 4;
#pragma unroll
    for (int r = 0; r < 4; ++r) {
        lds_h[(hrow + r) * 72 +  0 + lr] = f2bf(fmaxf(acc0[r] + lds_b1[ 0 + lr], 0.f));
        lds_h[(hrow + r) * 72 + 16 + lr] = f2bf(fmaxf(acc1[r] + lds_b1[16 + lr], 0.f));
        lds_h[(hrow + r) * 72 + 32 + lr] = f2bf(fmaxf(acc2[r] + lds_b1[32 + lr], 0.f));
        lds_h[(hrow + r) * 72 + 48 + lr] = f2bf(fmaxf(acc3[r] + lds_b1[48 + lr], 0.f));
    }
    __syncthreads();
    f32x4 o = {0.f, 0.f, 0.f, 0.f};
#pragma unroll
    for (int ks = 0; ks < 2; ++ks) {
        bf16x8 a = ld_bf8(lds_h + (16 * w + lr) * 72 + ks * 32 + lg * 8);
        bf16x8 b = ld_bf8(lds_w2t + lr * 72 + ks * 32 + lg * 8);
        o = __builtin_amdgcn_mfma_f32_16x16x32_bf16(a, b, o, 0, 0, 0);
    }
    const float b2v = lds_b2[lr];
#pragma unroll
    for (int r = 0; r < 4; ++r)
        outp[(hrow + r) * 16 + lr] = sigmoidf_(o[r] + b2v);
}

__global__ __launch_bounds__(192) void y3_fallback_kernel(
    const float* __restrict__ x2, const float* __restrict__ x3,
    const float* __restrict__ W1, const float* __restrict__ b1,
    const float* __restrict__ W2, const float* __restrict__ b2,
    float* __restrict__ out)
{
    __shared__ __align__(16) unsigned short lds_in[48 * 200];
    __shared__ __align__(16) unsigned short lds_w1t[64 * 200];
    __shared__ __align__(16) unsigned short lds_w2t[16 * 72];
    __shared__ __align__(16) unsigned short lds_h[48 * 72];
    __shared__ float lds_b1[64];
    __shared__ float lds_b2[16];
    const int t = threadIdx.x;
#pragma unroll 4
    for (int p = 0; p < 32; ++p) {
        int e = p * 192 + t;
        int h = e & 63, c2 = e >> 6;
        *(unsigned int*)(lds_w1t + h * 200 + 2 * c2) =
            pk2(W1[(2 * c2) * 64 + h], W1[(2 * c2 + 1) * 64 + h]);
    }
    for (int p = 0; p < 3; ++p) {
        int e = p * 192 + t;
        if (e < 512) {
            int n = e & 15, k2 = e >> 4;
            *(unsigned int*)(lds_w2t + n * 72 + 2 * k2) =
                pk2(W2[(2 * k2) * 16 + n], W2[(2 * k2 + 1) * 16 + n]);
        }
    }
    if (t < 64) lds_b1[t] = b1[t];
    if (t < 16) lds_b2[t] = b2[t];
    const int k = t >> 2, c4 = (t & 3) * 4;
#define STAGE3(PTR, BASE, KSTR, CH) do {                                       \
        const float4 v = *(const float4*)((PTR) + (BASE) + k * (KSTR) + c4);   \
        *(uint2*)(lds_in + k * 200 + (CH) + c4) =                              \
            make_uint2(pk2(v.x, v.y), pk2(v.z, v.w));                          \
    } while (0)
    for (int it = 0; it < 9; ++it) {
        const int g = blockIdx.x * 9 + it;
        const int b = g / 2304, rg = g % 2304, i = rg / 48, j = rg % 48;
        const float* xb2 = x2 + b * 36864;
        const float* xb3 = x3 + b * 1769472;
        __syncthreads();
        STAGE3(xb2, i * 768 + j * 16, 0,       0);
        STAGE3(xb3, i * 36864 + j * 768, 16,   16);
        STAGE3(xb2, i * 768, 16,               32);
        STAGE3(xb3, i * 36864 + j * 16, 768,   48);
        STAGE3(xb2, j * 768 + i * 16, 0,       64);
        STAGE3(xb3, j * 36864 + i * 768, 16,   80);
        STAGE3(xb2, i * 16, 768,               96);
        STAGE3(xb3, i * 768 + j * 16, 36864,   112);
        STAGE3(xb2, j * 768, 16,               128);
        STAGE3(xb3, j * 36864 + i * 16, 768,   144);
        STAGE3(xb2, j * 16, 768,               160);
        STAGE3(xb3, j * 768 + i * 16, 36864,   176);
        __syncthreads();
        mlp_head<6>(lds_in, lds_w1t, lds_w2t, lds_b1, lds_b2, lds_h,
                    out + (size_t)g * 768);
    }
#undef STAGE3
}

__global__ __launch_bounds__(192) void y2_kernel(
    const float* __restrict__ x1, const float* __restrict__ x2,
    const float* __restrict__ x3,
    const float* __restrict__ W1, const float* __restrict__ b1,
    const float* __restrict__ W2, const float* __restrict__ b2,
    float* __restrict__ out)
{
    __shared__ __align__(16) unsigned short lds_in[48 * 136];
    __shared__ __align__(16) unsigned short lds_w1t[64 * 136];
    __shared__ __align__(16) unsigned short lds_w2t[16 * 72];
    __shared__ __align__(16) unsigned short lds_h[48 * 72];
    __shared__ float lds_b1[64];
    __shared__ float lds_b2[16];
    const int t = threadIdx.x;
    const int b = blockIdx.x / 48, i = blockIdx.x % 48;
#pragma unroll 2
    for (int p = 0; p < 22; ++p) {
        int e = p * 192 + t;
        if (e < 4096) {
            int h = e & 63, c2 = e >> 6;
            *(unsigned int*)(lds_w1t + h * 136 + 2 * c2) =
                pk2(W1[(2 * c2) * 64 + h], W1[(2 * c2 + 1) * 64 + h]);
        }
    }
    for (int p = 0; p < 3; ++p) {
        int e = p * 192 + t;
        if (e < 512) {
            int n = e & 15, k2 = e >> 4;
            *(unsigned int*)(lds_w2t + n * 72 + 2 * k2) =
                pk2(W2[(2 * k2) * 16 + n], W2[(2 * k2 + 1) * 16 + n]);
        }
    }
    if (t < 64) lds_b1[t] = b1[t];
    if (t < 16) lds_b2[t] = b2[t];
    const int j = t >> 2, c4 = (t & 3) * 4;
    const float* xb2 = x2 + b * 36864;
#define STAGE2(PTR, BASE, JSTR, CH) do {                                       \
        const float4 v = *(const float4*)((PTR) + (BASE) + j * (JSTR) + c4);   \
        *(uint2*)(lds_in + j * 136 + (CH) + c4) =                              \
            make_uint2(pk2(v.x, v.y), pk2(v.z, v.w));                          \
    } while (0)
    STAGE2(x1, b * 768 + i * 16, 0,  0);
    STAGE2(xb2, i * 768, 16,         16);
    STAGE2(x1, b * 768, 16,          64);
    STAGE2(xb2, i * 16, 768,         80);
#undef STAGE2
    {
        const float* pa = x3 + b * 1769472 + (i * 48 + j) * 768 + c4;
        const float* pb = x3 + b * 1769472 + (j * 48 + i) * 768 + c4;
        float exa[4], faa[4], exb[4], fab[4];
#pragma unroll
        for (int u = 0; u < 4; ++u) {
            exa[u] = -__builtin_inff(); faa[u] = __builtin_inff();
            exb[u] = -__builtin_inff(); fab[u] = __builtin_inff();
        }
        for (int kk = 0; kk < 48; ++kk) {
            const bool m = (i != j) & (i != kk) & (j != kk);
            const float4 va = *(const float4*)(pa + kk * 16);
            const float4 vb = *(const float4*)(pb + kk * 16);
            const float av[4] = {va.x, va.y, va.z, va.w};
            const float bv[4] = {vb.x, vb.y, vb.z, vb.w};
#pragma unroll
            for (int u = 0; u < 4; ++u) {
                exa[u] = fmaxf(exa[u], m ? av[u] : 0.f);
                faa[u] = fminf(faa[u], m ? av[u] : 1.f);
                exb[u] = fmaxf(exb[u], m ? bv[u] : 0.f);
                fab[u] = fminf(fab[u], m ? bv[u] : 1.f);
            }
        }
#pragma unroll
        for (int u = 0; u < 4; ++u) {
            const int c = c4 + u;
            *(unsigned int*)(lds_in + j * 136 + 32 + 2 * c) = pk2(exa[u], faa[u]);
            *(unsigned int*)(lds_in + j * 136 + 96 + 2 * c) = pk2(exb[u], fab[u]);
        }
    }
    __syncthreads();
    mlp_head<4>(lds_in, lds_w1t, lds_w2t, lds_b1, lds_b2, lds_h,
                out + (size_t)blockIdx.x * 768);
}

// ---------------------------------------------------------------------------
extern "C" void kernel_launch(void* const* d_in, const int* in_sizes, int n_in,
                              void* d_out, int out_size, void* d_ws, size_t ws_size,
                              hipStream_t stream) {
    (void)in_sizes; (void)n_in; (void)out_size;
    const float* x0 = (const float*)d_in[0];
    const float* x1 = (const float*)d_in[1];
    const float* x2 = (const float*)d_in[2];
    const float* x3 = (const float*)d_in[3];
    const float* W1_0 = (const float*)d_in[4];
    const float* b1_0 = (const float*)d_in[5];
    const float* W2_0 = (const float*)d_in[6];
    const float* b2_0 = (const float*)d_in[7];
    const float* W1_1 = (const float*)d_in[8];
    const float* b1_1 = (const float*)d_in[9];
    const float* W2_1 = (const float*)d_in[10];
    const float* b2_1 = (const float*)d_in[11];
    const float* W1_2 = (const float*)d_in[12];
    const float* b1_2 = (const float*)d_in[13];
    const float* W2_2 = (const float*)d_in[14];
    const float* b2_2 = (const float*)d_in[15];
    const float* W1_3 = (const float*)d_in[16];
    const float* b1_3 = (const float*)d_in[17];
    const float* W2_3 = (const float*)d_in[18];
    const float* b2_3 = (const float*)d_in[19];
    float* out = (float*)d_out;

    // Output layout: y0 [0,64) | y1 [64,3136) | y2 [3136,150592) | y3 [150592,...)
    // ws layout (shorts from base):
    //   A fp32 [2*NPAIR] | B [NPAIR] | C [NPAIR] | red3 [NRED3]
    //   | X0 [NX3] | XA [NX3] | XB [NX3]
    const size_t ws_mid  = (size_t)8 * NPAIR + (size_t)2 * NRED3;
    const size_t ws_full = ws_mid + (size_t)6 * NX3;
    if (ws_size >= ws_mid) {
        float* wsA = (float*)d_ws;
        unsigned short* wsB = (unsigned short*)d_ws + 2 * NPAIR;
        unsigned short* wsC = wsB + NPAIR;
        unsigned short* red3 = (unsigned short*)d_ws + 4 * NPAIR;
        if (ws_size >= ws_full) {
            unsigned short* X0 = red3 + NRED3;
            unsigned short* XA = X0 + NX3;
            unsigned short* XB = XA + NX3;
            pre_kernel<<<11520, 256, 0, stream>>>(x2, x3, W1_3, b1_3,
                                                  wsA, wsB, wsC, X0, XA, XB, red3);
            main_kernel<<<1349, 192, 0, stream>>>(X0, XA, XB, W1_3, W2_3, b2_3,
                                                  wsA, wsB, wsC,
                                                  x1, x2, W1_2, b1_2, W2_2, b2_2, red3,
                                                  x0, W1_0, b1_0, W2_0, b2_0,
                                                  W1_1, b1_1, W2_1, b2_1, out);
        } else {
            phaseA_kernel<<<2304, 256, 0, stream>>>(x2, W1_3, b1_3, wsA, wsB, wsC);
            y3_gather_kernel<<<2304, 192, 0, stream>>>(x3, W1_3, W2_3, b2_3,
                                                       wsA, wsB, wsC, out + 150592);
            red3_kernel<<<576, 256, 0, stream>>>(x3, red3);
            y2_mlp_kernel<<<192, 192, 0, stream>>>(x1, x2, W1_2, b1_2, W2_2, b2_2,
                                                   red3, out + 3136);
            y01_kernel<<<5, 192, 0, stream>>>(x0, x1, x2, W1_0, b1_0, W2_0, b2_0,
                                              W1_1, b1_1, W2_1, b2_1, out);
        }
    } else {
        y3_fallback_kernel<<<1024, 192, 0, stream>>>(x2, x3, W1_3, b1_3, W2_3, b2_3,
                                                     out + 150592);
        y2_kernel<<<192, 192, 0, stream>>>(x1, x2, x3, W1_2, b1_2, W2_2, b2_2,
                                           out + 3136);
        y01_kernel<<<5, 192, 0, stream>>>(x0, x1, x2, W1_0, b1_0, W2_0, b2_0,
                                          W1_1, b1_1, W2_1, b2_1, out);
    }
}